// Round 1
// baseline (564.117 us; speedup 1.0000x reference)
//
#include <hip/hip_runtime.h>
#include <stdint.h>

// MultiHeadAttention: B=4, T=2048, C=1024, H=16, D=64, causal, scale=1/8.
// Pipeline: cast->bf16, QKV GEMM (MFMA), flash attention (MFMA+online softmax),
// out-proj GEMM (MFMA) + bias -> fp32.
//
// MFMA 16x16x32 bf16 layouts (HW-verified per guide):
//   A frag: m = lane&15, k = (lane>>4)*8 + j   (8 bf16 / lane)
//   B frag: n = lane&15, k = (lane>>4)*8 + j
//   C/D:    col = lane&15, row = (lane>>4)*4 + reg

typedef __attribute__((ext_vector_type(8))) short bf16x8;
typedef __attribute__((ext_vector_type(4))) float f32x4;

#define SCALE_F 0.125f

__device__ __forceinline__ short f2bf(float f) {
  union { float f; unsigned u; } c; c.f = f;
  unsigned u = c.u;
  unsigned r = (u + 0x7fffu + ((u >> 16) & 1u)) >> 16;
  return (short)(unsigned short)r;
}

__global__ __launch_bounds__(256) void cast_f32_to_bf16(
    const float* __restrict__ src, short* __restrict__ dst, int n4) {
  int i = blockIdx.x * 256 + threadIdx.x;
  if (i >= n4) return;
  float4 f = ((const float4*)src)[i];
  short4 o;
  o.x = f2bf(f.x); o.y = f2bf(f.y); o.z = f2bf(f.z); o.w = f2bf(f.w);
  ((short4*)dst)[i] = o;
}

// ---------------------------------------------------------------------------
// GEMM (B^T form): C[m,n] = sum_k A[m,k] * Bw[n,k].  A:[M,1024] Bw:[N,1024]
// 128x128 tile, BK=32, 256 thr = 4 waves in 2x2, each wave 64x64 (4x4 MFMA).
// ---------------------------------------------------------------------------

// QKV GEMM: M=8192 (b*2048+t), N=3072 (o). Epilogue scatters to q/k/v [B,H,T,D] bf16.
__global__ __launch_bounds__(256) void gemm_qkv(
    const short* __restrict__ A, const short* __restrict__ Bw,
    short* __restrict__ Qo, short* __restrict__ Ko, short* __restrict__ Vo) {
  const int K = 1024;
  __shared__ short lA[128 * 32];
  __shared__ short lB[128 * 32];
  const int tid = threadIdx.x;
  const int lane = tid & 63;
  const int wave = tid >> 6;
  const int m0 = blockIdx.y * 128;
  const int n0 = blockIdx.x * 128;
  const int wm = (wave >> 1) * 64;
  const int wn = (wave & 1) * 64;
  const int mrow = lane & 15;
  const int kq = lane >> 4;

  f32x4 acc[4][4];
#pragma unroll
  for (int i = 0; i < 4; ++i)
#pragma unroll
    for (int j = 0; j < 4; ++j) acc[i][j] = (f32x4){0.f, 0.f, 0.f, 0.f};

  for (int k0 = 0; k0 < K; k0 += 32) {
#pragma unroll
    for (int call = 0; call < 2; ++call) {
      const int c = call * 256 + tid;  // 512 chunks of 8 bf16 (16B)
      bf16x8 va = *(const bf16x8*)(A + (size_t)(m0 + (c >> 2)) * K + k0 + (c & 3) * 8);
      bf16x8 vb = *(const bf16x8*)(Bw + (size_t)(n0 + (c >> 2)) * K + k0 + (c & 3) * 8);
      *(bf16x8*)&lA[c * 8] = va;
      *(bf16x8*)&lB[c * 8] = vb;
    }
    __syncthreads();
    bf16x8 af[4], bfr[4];
#pragma unroll
    for (int i = 0; i < 4; ++i)
      af[i] = *(const bf16x8*)&lA[(wm + i * 16 + mrow) * 32 + kq * 8];
#pragma unroll
    for (int j = 0; j < 4; ++j)
      bfr[j] = *(const bf16x8*)&lB[(wn + j * 16 + mrow) * 32 + kq * 8];
#pragma unroll
    for (int i = 0; i < 4; ++i)
#pragma unroll
      for (int j = 0; j < 4; ++j)
        acc[i][j] = __builtin_amdgcn_mfma_f32_16x16x32_bf16(af[i], bfr[j], acc[i][j], 0, 0, 0);
    __syncthreads();
  }

#pragma unroll
  for (int i = 0; i < 4; ++i) {
    const int m = m0 + wm + i * 16 + kq * 4;  // +r below, stays in same b (m%4==0)
    const int b = m >> 11;
    const int t = m & 2047;
#pragma unroll
    for (int j = 0; j < 4; ++j) {
      const int o = n0 + wn + j * 16 + mrow;
      const int which = o >> 10;          // 0=q 1=k 2=v
      const int c = o & 1023;
      const int h = c >> 6;
      const int d = c & 63;
      short* dst = which == 0 ? Qo : (which == 1 ? Ko : Vo);
      const size_t off = ((size_t)(b * 16 + h) * 2048 + t) * 64 + d;
#pragma unroll
      for (int r = 0; r < 4; ++r)
        dst[off + (size_t)r * 64] = f2bf(acc[i][j][r]);
    }
  }
}

// Out-proj GEMM: M=8192, N=1024, + bias, fp32 output.
__global__ __launch_bounds__(256) void gemm_out(
    const short* __restrict__ A, const short* __restrict__ Bw,
    const float* __restrict__ bias, float* __restrict__ Out) {
  const int K = 1024;
  __shared__ short lA[128 * 32];
  __shared__ short lB[128 * 32];
  const int tid = threadIdx.x;
  const int lane = tid & 63;
  const int wave = tid >> 6;
  const int m0 = blockIdx.y * 128;
  const int n0 = blockIdx.x * 128;
  const int wm = (wave >> 1) * 64;
  const int wn = (wave & 1) * 64;
  const int mrow = lane & 15;
  const int kq = lane >> 4;

  f32x4 acc[4][4];
#pragma unroll
  for (int i = 0; i < 4; ++i)
#pragma unroll
    for (int j = 0; j < 4; ++j) acc[i][j] = (f32x4){0.f, 0.f, 0.f, 0.f};

  for (int k0 = 0; k0 < K; k0 += 32) {
#pragma unroll
    for (int call = 0; call < 2; ++call) {
      const int c = call * 256 + tid;
      bf16x8 va = *(const bf16x8*)(A + (size_t)(m0 + (c >> 2)) * K + k0 + (c & 3) * 8);
      bf16x8 vb = *(const bf16x8*)(Bw + (size_t)(n0 + (c >> 2)) * K + k0 + (c & 3) * 8);
      *(bf16x8*)&lA[c * 8] = va;
      *(bf16x8*)&lB[c * 8] = vb;
    }
    __syncthreads();
    bf16x8 af[4], bfr[4];
#pragma unroll
    for (int i = 0; i < 4; ++i)
      af[i] = *(const bf16x8*)&lA[(wm + i * 16 + mrow) * 32 + kq * 8];
#pragma unroll
    for (int j = 0; j < 4; ++j)
      bfr[j] = *(const bf16x8*)&lB[(wn + j * 16 + mrow) * 32 + kq * 8];
#pragma unroll
    for (int i = 0; i < 4; ++i)
#pragma unroll
      for (int j = 0; j < 4; ++j)
        acc[i][j] = __builtin_amdgcn_mfma_f32_16x16x32_bf16(af[i], bfr[j], acc[i][j], 0, 0, 0);
    __syncthreads();
  }

#pragma unroll
  for (int i = 0; i < 4; ++i) {
    const int m = m0 + wm + i * 16 + kq * 4;
#pragma unroll
    for (int j = 0; j < 4; ++j) {
      const int n = n0 + wn + j * 16 + mrow;
      const float bb = bias[n];
#pragma unroll
      for (int r = 0; r < 4; ++r)
        Out[(size_t)(m + r) * 1024 + n] = acc[i][j][r] + bb;
    }
  }
}

// ---------------------------------------------------------------------------
// Flash attention. Grid: (T/64, B*H). Block 256 = 4 waves, each wave owns 16
// q-rows. K-tile 64 keys staged in LDS [key][64]; V staged transposed [d][key]
// so PV B-fragments are contiguous ds_read_b128. P round-trips through
// wave-private LDS (C-layout -> A-layout). Online softmax state per C-row.
// ---------------------------------------------------------------------------
__global__ __launch_bounds__(256) void flash_attn(
    const short* __restrict__ Qg, const short* __restrict__ Kg,
    const short* __restrict__ Vg, short* __restrict__ Og) {
  const int T = 2048, D = 64;
  __shared__ short lK[64 * 64];
  __shared__ short lVt[64 * 64];
  __shared__ short lP[4 * 16 * 64];
  const int tid = threadIdx.x;
  const int lane = tid & 63;
  const int wave = tid >> 6;
  const int qt = blockIdx.x;
  const int bh = blockIdx.y;
  const int q0 = qt * 64;
  const int mrow = lane & 15;
  const int kq = lane >> 4;
  const size_t base = (size_t)bh * T * D;

  bf16x8 aq0, aq1;  // Q A-fragments for k=0..31, 32..63
  {
    const short* qp = Qg + base + (size_t)(q0 + wave * 16 + mrow) * D + kq * 8;
    aq0 = *(const bf16x8*)qp;
    aq1 = *(const bf16x8*)(qp + 32);
  }

  float m_s[4], l_s[4];
  f32x4 acc[4];
#pragma unroll
  for (int r = 0; r < 4; ++r) { m_s[r] = -1e30f; l_s[r] = 0.f; }
#pragma unroll
  for (int jd = 0; jd < 4; ++jd) acc[jd] = (f32x4){0.f, 0.f, 0.f, 0.f};

  for (int kt = 0; kt <= qt; ++kt) {
    const size_t kbase = base + (size_t)kt * 64 * D;
#pragma unroll
    for (int call = 0; call < 2; ++call) {
      const int c = call * 256 + tid;  // 512 chunks: key=c>>3, dchunk=c&7
      const int key = c >> 3, dc = c & 7;
      bf16x8 kv = *(const bf16x8*)(Kg + kbase + (size_t)key * D + dc * 8);
      *(bf16x8*)&lK[c * 8] = kv;
      bf16x8 vv = *(const bf16x8*)(Vg + kbase + (size_t)key * D + dc * 8);
#pragma unroll
      for (int jj = 0; jj < 8; ++jj)
        lVt[(dc * 8 + jj) * 64 + key] = vv[jj];  // transpose store
    }
    __syncthreads();

    // S = Q K^T (4 key-tiles of 16)
    f32x4 sc[4];
#pragma unroll
    for (int j = 0; j < 4; ++j) {
      bf16x8 kb0 = *(const bf16x8*)&lK[(j * 16 + mrow) * 64 + kq * 8];
      bf16x8 kb1 = *(const bf16x8*)&lK[(j * 16 + mrow) * 64 + 32 + kq * 8];
      f32x4 s = (f32x4){0.f, 0.f, 0.f, 0.f};
      s = __builtin_amdgcn_mfma_f32_16x16x32_bf16(aq0, kb0, s, 0, 0, 0);
      s = __builtin_amdgcn_mfma_f32_16x16x32_bf16(aq1, kb1, s, 0, 0, 0);
      sc[j] = s;
    }

    const int qrow = q0 + wave * 16 + kq * 4;  // C-layout row base
    if (kt == qt) {
#pragma unroll
      for (int j = 0; j < 4; ++j) {
        const int key = kt * 64 + j * 16 + mrow;
#pragma unroll
        for (int r = 0; r < 4; ++r)
          sc[j][r] = (key > qrow + r) ? -1e30f : sc[j][r] * SCALE_F;
      }
    } else {
#pragma unroll
      for (int j = 0; j < 4; ++j)
#pragma unroll
        for (int r = 0; r < 4; ++r) sc[j][r] *= SCALE_F;
    }

    // row max across 16 lanes of the quad group
    float mx[4];
#pragma unroll
    for (int r = 0; r < 4; ++r)
      mx[r] = fmaxf(fmaxf(sc[0][r], sc[1][r]), fmaxf(sc[2][r], sc[3][r]));
#pragma unroll
    for (int off = 1; off < 16; off <<= 1)
#pragma unroll
      for (int r = 0; r < 4; ++r) mx[r] = fmaxf(mx[r], __shfl_xor(mx[r], off));

    float alpha[4], rs[4];
#pragma unroll
    for (int r = 0; r < 4; ++r) {
      const float mn = fmaxf(m_s[r], mx[r]);
      alpha[r] = __expf(m_s[r] - mn);
      m_s[r] = mn;
    }
#pragma unroll
    for (int j = 0; j < 4; ++j)
#pragma unroll
      for (int r = 0; r < 4; ++r) sc[j][r] = __expf(sc[j][r] - m_s[r]);
#pragma unroll
    for (int r = 0; r < 4; ++r)
      rs[r] = sc[0][r] + sc[1][r] + sc[2][r] + sc[3][r];
#pragma unroll
    for (int off = 1; off < 16; off <<= 1)
#pragma unroll
      for (int r = 0; r < 4; ++r) rs[r] += __shfl_xor(rs[r], off);
#pragma unroll
    for (int r = 0; r < 4; ++r) l_s[r] = l_s[r] * alpha[r] + rs[r];
#pragma unroll
    for (int jd = 0; jd < 4; ++jd)
#pragma unroll
      for (int r = 0; r < 4; ++r) acc[jd][r] *= alpha[r];

    // P: C-layout regs -> wave-private LDS -> A-layout frags (same-wave DS is in-order)
    short* pw = &lP[wave * 1024];
#pragma unroll
    for (int j = 0; j < 4; ++j)
#pragma unroll
      for (int r = 0; r < 4; ++r)
        pw[(kq * 4 + r) * 64 + j * 16 + mrow] = f2bf(sc[j][r]);

#pragma unroll
    for (int jd = 0; jd < 4; ++jd) {
#pragma unroll
      for (int ch = 0; ch < 2; ++ch) {
        bf16x8 pa = *(const bf16x8*)&lP[wave * 1024 + mrow * 64 + ch * 32 + kq * 8];
        bf16x8 vb = *(const bf16x8*)&lVt[(jd * 16 + mrow) * 64 + ch * 32 + kq * 8];
        acc[jd] = __builtin_amdgcn_mfma_f32_16x16x32_bf16(pa, vb, acc[jd], 0, 0, 0);
      }
    }
    __syncthreads();
  }

  // epilogue: O /= l, write att_out bf16 at [b, t, h*64+d]
  const int b = bh >> 4;
  const int h = bh & 15;
#pragma unroll
  for (int r = 0; r < 4; ++r) {
    const int t = q0 + wave * 16 + kq * 4 + r;
    const float inv = 1.0f / l_s[r];
#pragma unroll
    for (int jd = 0; jd < 4; ++jd) {
      const int col = h * 64 + jd * 16 + mrow;
      Og[((size_t)b * 2048 + t) * 1024 + col] = f2bf(acc[jd][r] * inv);
    }
  }
}

extern "C" void kernel_launch(void* const* d_in, const int* in_sizes, int n_in,
                              void* d_out, int out_size, void* d_ws, size_t ws_size,
                              hipStream_t stream) {
  const float* x = (const float*)d_in[0];
  const float* w_qkv = (const float*)d_in[1];
  const float* w_out = (const float*)d_in[2];
  const float* b_out = (const float*)d_in[3];
  float* out = (float*)d_out;

  char* ws = (char*)d_ws;
  const size_t NX = 8192ull * 1024;   // x / att elements
  const size_t NWQ = 3072ull * 1024;
  const size_t NWO = 1024ull * 1024;
  const size_t NQ = 64ull * 2048 * 64;
  size_t off = 0;
  short* xb    = (short*)(ws + off); off += NX * 2;
  short* wqkvb = (short*)(ws + off); off += NWQ * 2;
  short* woutb = (short*)(ws + off); off += NWO * 2;
  short* q     = (short*)(ws + off); off += NQ * 2;
  short* k     = (short*)(ws + off); off += NQ * 2;
  short* v     = (short*)(ws + off); off += NQ * 2;
  short* attb  = (short*)(ws + off); off += NX * 2;
  if (off > ws_size) return;  // ws too small: fail visibly rather than corrupt

  cast_f32_to_bf16<<<(int)(NX / 4 / 256), 256, 0, stream>>>(x, xb, (int)(NX / 4));
  cast_f32_to_bf16<<<(int)(NWQ / 4 / 256), 256, 0, stream>>>(w_qkv, wqkvb, (int)(NWQ / 4));
  cast_f32_to_bf16<<<(int)(NWO / 4 / 256), 256, 0, stream>>>(w_out, woutb, (int)(NWO / 4));
  gemm_qkv<<<dim3(24, 64), 256, 0, stream>>>(xb, wqkvb, q, k, v);
  flash_attn<<<dim3(32, 64), 256, 0, stream>>>(q, k, v, attb);
  gemm_out<<<dim3(8, 64), 256, 0, stream>>>(attb, woutb, b_out, out);
}

// Round 3
// 351.587 us; speedup vs baseline: 1.6045x; 1.6045x over previous
//
#include <hip/hip_runtime.h>
#include <stdint.h>

// MultiHeadAttention: B=4, T=2048, C=1024, H=16, D=64, causal, scale=1/8.
// R3 = R2 with __builtin_amdgcn_exp2f (glibc macro collision fix):
// global_load_lds staging everywhere, V pre-transposed in global,
// padded P LDS (stride 72), double-buffered flash K/V (1 barrier/iter),
// balanced causal pairing (qt, 31-qt), exp2-domain softmax.
//
// MFMA 16x16x32 bf16 layouts:
//   A frag: m = lane&15, k = (lane>>4)*8 + j
//   B frag: n = lane&15, k = (lane>>4)*8 + j
//   C/D:    col = lane&15, row = (lane>>4)*4 + reg

typedef __attribute__((ext_vector_type(8))) short bf16x8;
typedef __attribute__((ext_vector_type(4))) float f32x4;

#define EXP2F(x) __builtin_amdgcn_exp2f(x)

__device__ __forceinline__ short f2bf(float f) {
  union { float f; unsigned u; } c; c.f = f;
  unsigned u = c.u;
  unsigned r = (u + 0x7fffu + ((u >> 16) & 1u)) >> 16;
  return (short)(unsigned short)r;
}

// async 16B global -> LDS (dest = wave-uniform base + lane*16)
__device__ __forceinline__ void llds16(const short* g, short* l) {
  __builtin_amdgcn_global_load_lds(
      (const __attribute__((address_space(1))) unsigned int*)g,
      (__attribute__((address_space(3))) unsigned int*)l, 16, 0, 0);
}

__global__ __launch_bounds__(256) void cast_f32_to_bf16(
    const float* __restrict__ src, short* __restrict__ dst, int n4) {
  int i = blockIdx.x * 256 + threadIdx.x;
  if (i >= n4) return;
  float4 f = ((const float4*)src)[i];
  short4 o;
  o.x = f2bf(f.x); o.y = f2bf(f.y); o.z = f2bf(f.z); o.w = f2bf(f.w);
  ((short4*)dst)[i] = o;
}

// V [bh][t][d=64] -> Vt [bh][d][t]. Tile 64x64 via LDS (stride 72).
__global__ __launch_bounds__(256) void transpose_v(
    const short* __restrict__ V, short* __restrict__ Vt) {
  const int T = 2048;
  __shared__ short lT[64 * 72];
  const int tid = threadIdx.x;
  const int t0 = blockIdx.x * 64;
  const int bh = blockIdx.y;
  const size_t ib = (size_t)bh * T * 64;
  const size_t ob = (size_t)bh * 64 * T;
#pragma unroll
  for (int call = 0; call < 2; ++call) {
    const int c = call * 256 + tid;          // t = c>>3, dchunk = c&7
    bf16x8 vv = *(const bf16x8*)(V + ib + (size_t)(t0 + (c >> 3)) * 64 + (c & 7) * 8);
#pragma unroll
    for (int jj = 0; jj < 8; ++jj)
      lT[((c & 7) * 8 + jj) * 72 + (c >> 3)] = vv[jj];
  }
  __syncthreads();
#pragma unroll
  for (int call = 0; call < 2; ++call) {
    const int c = call * 256 + tid;          // d = c>>3, tchunk = c&7
    bf16x8 o = *(const bf16x8*)&lT[(c >> 3) * 72 + (c & 7) * 8];
    *(bf16x8*)(Vt + ob + (size_t)(c >> 3) * T + t0 + (c & 7) * 8) = o;
  }
}

// ---------------------------------------------------------------------------
// GEMM (B^T): C[m,n] = sum_k A[m,k]*Bw[n,k]. 128x128 tile, BK=32,
// 4 waves 2x2, global_load_lds width-16 staging (m97 pattern).
// ---------------------------------------------------------------------------
__global__ __launch_bounds__(256) void gemm_qkv(
    const short* __restrict__ A, const short* __restrict__ Bw,
    short* __restrict__ Qo, short* __restrict__ Ko, short* __restrict__ Vo) {
  const int K = 1024;
  __shared__ short lA[128 * 32];
  __shared__ short lB[128 * 32];
  const int tid = threadIdx.x;
  const int lane = tid & 63;
  const int wave = tid >> 6;
  const int m0 = blockIdx.y * 128;
  const int n0 = blockIdx.x * 128;
  const int wm = (wave >> 1) * 64;
  const int wn = (wave & 1) * 64;
  const int mrow = lane & 15;
  const int kq = lane >> 4;

  f32x4 acc[4][4];
#pragma unroll
  for (int i = 0; i < 4; ++i)
#pragma unroll
    for (int j = 0; j < 4; ++j) acc[i][j] = (f32x4){0.f, 0.f, 0.f, 0.f};

  for (int k0 = 0; k0 < K; k0 += 32) {
#pragma unroll
    for (int call = 0; call < 2; ++call) {
      const int cb = call * 256 + wave * 64;
      const int c = cb + lane;
      llds16(A + (size_t)(m0 + (c >> 2)) * K + k0 + (c & 3) * 8, &lA[cb * 8]);
      llds16(Bw + (size_t)(n0 + (c >> 2)) * K + k0 + (c & 3) * 8, &lB[cb * 8]);
    }
    __syncthreads();
    bf16x8 af[4], bfr[4];
#pragma unroll
    for (int i = 0; i < 4; ++i)
      af[i] = *(const bf16x8*)&lA[(wm + i * 16 + mrow) * 32 + kq * 8];
#pragma unroll
    for (int j = 0; j < 4; ++j)
      bfr[j] = *(const bf16x8*)&lB[(wn + j * 16 + mrow) * 32 + kq * 8];
#pragma unroll
    for (int i = 0; i < 4; ++i)
#pragma unroll
      for (int j = 0; j < 4; ++j)
        acc[i][j] = __builtin_amdgcn_mfma_f32_16x16x32_bf16(af[i], bfr[j], acc[i][j], 0, 0, 0);
    __syncthreads();
  }

#pragma unroll
  for (int i = 0; i < 4; ++i) {
    const int m = m0 + wm + i * 16 + kq * 4;
    const int b = m >> 11;
    const int t = m & 2047;
#pragma unroll
    for (int j = 0; j < 4; ++j) {
      const int o = n0 + wn + j * 16 + mrow;
      const int which = o >> 10;          // 0=q 1=k 2=v
      const int c = o & 1023;
      const int h = c >> 6;
      const int d = c & 63;
      short* dst = which == 0 ? Qo : (which == 1 ? Ko : Vo);
      const size_t off = ((size_t)(b * 16 + h) * 2048 + t) * 64 + d;
#pragma unroll
      for (int r = 0; r < 4; ++r)
        dst[off + (size_t)r * 64] = f2bf(acc[i][j][r]);
    }
  }
}

__global__ __launch_bounds__(256) void gemm_out(
    const short* __restrict__ A, const short* __restrict__ Bw,
    const float* __restrict__ bias, float* __restrict__ Out) {
  const int K = 1024;
  __shared__ short lA[128 * 32];
  __shared__ short lB[128 * 32];
  const int tid = threadIdx.x;
  const int lane = tid & 63;
  const int wave = tid >> 6;
  const int m0 = blockIdx.y * 128;
  const int n0 = blockIdx.x * 128;
  const int wm = (wave >> 1) * 64;
  const int wn = (wave & 1) * 64;
  const int mrow = lane & 15;
  const int kq = lane >> 4;

  f32x4 acc[4][4];
#pragma unroll
  for (int i = 0; i < 4; ++i)
#pragma unroll
    for (int j = 0; j < 4; ++j) acc[i][j] = (f32x4){0.f, 0.f, 0.f, 0.f};

  for (int k0 = 0; k0 < K; k0 += 32) {
#pragma unroll
    for (int call = 0; call < 2; ++call) {
      const int cb = call * 256 + wave * 64;
      const int c = cb + lane;
      llds16(A + (size_t)(m0 + (c >> 2)) * K + k0 + (c & 3) * 8, &lA[cb * 8]);
      llds16(Bw + (size_t)(n0 + (c >> 2)) * K + k0 + (c & 3) * 8, &lB[cb * 8]);
    }
    __syncthreads();
    bf16x8 af[4], bfr[4];
#pragma unroll
    for (int i = 0; i < 4; ++i)
      af[i] = *(const bf16x8*)&lA[(wm + i * 16 + mrow) * 32 + kq * 8];
#pragma unroll
    for (int j = 0; j < 4; ++j)
      bfr[j] = *(const bf16x8*)&lB[(wn + j * 16 + mrow) * 32 + kq * 8];
#pragma unroll
    for (int i = 0; i < 4; ++i)
#pragma unroll
      for (int j = 0; j < 4; ++j)
        acc[i][j] = __builtin_amdgcn_mfma_f32_16x16x32_bf16(af[i], bfr[j], acc[i][j], 0, 0, 0);
    __syncthreads();
  }

#pragma unroll
  for (int i = 0; i < 4; ++i) {
    const int m = m0 + wm + i * 16 + kq * 4;
#pragma unroll
    for (int j = 0; j < 4; ++j) {
      const int n = n0 + wn + j * 16 + mrow;
      const float bb = bias[n];
#pragma unroll
      for (int r = 0; r < 4; ++r)
        Out[(size_t)(m + r) * 1024 + n] = acc[i][j][r] + bb;
    }
  }
}

// ---------------------------------------------------------------------------
// Flash attention. Grid (16, B*H): block handles q-tiles qtA=bx and qtB=31-bx
// (constant 33 K-iterations). 4 waves x 16 q-rows. Double-buffered K/Vt tiles
// staged via global_load_lds; ONE barrier per iteration. P via wave-private
// LDS, row stride 72 (2-way banks = free, 16B-aligned reads).
// ---------------------------------------------------------------------------
__global__ __launch_bounds__(256) void flash_attn(
    const short* __restrict__ Qg, const short* __restrict__ Kg,
    const short* __restrict__ Vtg, short* __restrict__ Og) {
  const int T = 2048;
  __shared__ short lK[2][64 * 64];
  __shared__ short lVt[2][64 * 64];
  __shared__ short lP[4 * 16 * 72];
  const int tid = threadIdx.x;
  const int lane = tid & 63;
  const int wave = tid >> 6;
  const int bh = blockIdx.y;
  const int mrow = lane & 15;
  const int kq = lane >> 4;
  const size_t base = (size_t)bh * T * 64;   // Q,K: [bh][t][d]
  const size_t vbase = (size_t)bh * 64 * T;  // Vt:  [bh][d][t]
  const float SL2E = 0.125f * 1.44269504089f;

  for (int seg = 0; seg < 2; ++seg) {
    const int qt = seg ? (31 - (int)blockIdx.x) : (int)blockIdx.x;
    const int q0 = qt * 64;

    bf16x8 aq0, aq1;
    {
      const short* qp = Qg + base + (size_t)(q0 + wave * 16 + mrow) * 64 + kq * 8;
      aq0 = *(const bf16x8*)qp;
      aq1 = *(const bf16x8*)(qp + 32);
    }

    float m_s[4], l_s[4];
    f32x4 acc[4];
#pragma unroll
    for (int r = 0; r < 4; ++r) { m_s[r] = -1e30f; l_s[r] = 0.f; }
#pragma unroll
    for (int jd = 0; jd < 4; ++jd) acc[jd] = (f32x4){0.f, 0.f, 0.f, 0.f};

    // prologue: stage tile 0 into buffer 0
#pragma unroll
    for (int call = 0; call < 2; ++call) {
      const int cb = call * 256 + wave * 64;
      const int c = cb + lane;
      llds16(Kg + base + (size_t)(c >> 3) * 64 + (c & 7) * 8, &lK[0][cb * 8]);
      llds16(Vtg + vbase + (size_t)(c >> 3) * T + (c & 7) * 8, &lVt[0][cb * 8]);
    }
    __syncthreads();

    for (int kt = 0; kt <= qt; ++kt) {
      const int bcur = kt & 1;
      if (kt < qt) {
        const int nt = kt + 1;
#pragma unroll
        for (int call = 0; call < 2; ++call) {
          const int cb = call * 256 + wave * 64;
          const int c = cb + lane;
          llds16(Kg + base + (size_t)(nt * 64 + (c >> 3)) * 64 + (c & 7) * 8,
                 &lK[bcur ^ 1][cb * 8]);
          llds16(Vtg + vbase + (size_t)(c >> 3) * T + nt * 64 + (c & 7) * 8,
                 &lVt[bcur ^ 1][cb * 8]);
        }
      }
      const short* K_ = lK[bcur];
      const short* Vt_ = lVt[bcur];

      // S = Q K^T (4 key sub-tiles of 16)
      f32x4 sc[4];
#pragma unroll
      for (int j = 0; j < 4; ++j) {
        bf16x8 kb0 = *(const bf16x8*)&K_[(j * 16 + mrow) * 64 + kq * 8];
        bf16x8 kb1 = *(const bf16x8*)&K_[(j * 16 + mrow) * 64 + 32 + kq * 8];
        f32x4 s = (f32x4){0.f, 0.f, 0.f, 0.f};
        s = __builtin_amdgcn_mfma_f32_16x16x32_bf16(aq0, kb0, s, 0, 0, 0);
        s = __builtin_amdgcn_mfma_f32_16x16x32_bf16(aq1, kb1, s, 0, 0, 0);
        sc[j] = s;
      }

      const int qrow = q0 + wave * 16 + kq * 4;
      if (kt == qt) {
#pragma unroll
        for (int j = 0; j < 4; ++j) {
          const int key = kt * 64 + j * 16 + mrow;
#pragma unroll
          for (int r = 0; r < 4; ++r)
            sc[j][r] = (key > qrow + r) ? -1e30f : sc[j][r] * SL2E;
        }
      } else {
#pragma unroll
        for (int j = 0; j < 4; ++j)
#pragma unroll
          for (int r = 0; r < 4; ++r) sc[j][r] *= SL2E;
      }

      float mx[4];
#pragma unroll
      for (int r = 0; r < 4; ++r)
        mx[r] = fmaxf(fmaxf(sc[0][r], sc[1][r]), fmaxf(sc[2][r], sc[3][r]));
#pragma unroll
      for (int off = 1; off < 16; off <<= 1)
#pragma unroll
        for (int r = 0; r < 4; ++r) mx[r] = fmaxf(mx[r], __shfl_xor(mx[r], off));

      float alpha[4], rs[4];
#pragma unroll
      for (int r = 0; r < 4; ++r) {
        const float mn = fmaxf(m_s[r], mx[r]);
        alpha[r] = EXP2F(m_s[r] - mn);
        m_s[r] = mn;
      }
#pragma unroll
      for (int j = 0; j < 4; ++j)
#pragma unroll
        for (int r = 0; r < 4; ++r) sc[j][r] = EXP2F(sc[j][r] - m_s[r]);
#pragma unroll
      for (int r = 0; r < 4; ++r)
        rs[r] = sc[0][r] + sc[1][r] + sc[2][r] + sc[3][r];
#pragma unroll
      for (int off = 1; off < 16; off <<= 1)
#pragma unroll
        for (int r = 0; r < 4; ++r) rs[r] += __shfl_xor(rs[r], off);
#pragma unroll
      for (int r = 0; r < 4; ++r) l_s[r] = l_s[r] * alpha[r] + rs[r];
#pragma unroll
      for (int jd = 0; jd < 4; ++jd)
#pragma unroll
        for (int r = 0; r < 4; ++r) acc[jd][r] *= alpha[r];

      // P: C-layout -> wave-private LDS (stride 72) -> A-layout frags
      short* pw = &lP[wave * 1152];
#pragma unroll
      for (int j = 0; j < 4; ++j)
#pragma unroll
        for (int r = 0; r < 4; ++r)
          pw[(kq * 4 + r) * 72 + j * 16 + mrow] = f2bf(sc[j][r]);

      bf16x8 pa[2];
#pragma unroll
      for (int ch = 0; ch < 2; ++ch)
        pa[ch] = *(const bf16x8*)&lP[wave * 1152 + mrow * 72 + ch * 32 + kq * 8];
#pragma unroll
      for (int jd = 0; jd < 4; ++jd) {
#pragma unroll
        for (int ch = 0; ch < 2; ++ch) {
          bf16x8 vb = *(const bf16x8*)&Vt_[(jd * 16 + mrow) * 64 + ch * 32 + kq * 8];
          acc[jd] = __builtin_amdgcn_mfma_f32_16x16x32_bf16(pa[ch], vb, acc[jd], 0, 0, 0);
        }
      }
      __syncthreads();
    }

    const int b = bh >> 4;
    const int h = bh & 15;
#pragma unroll
    for (int r = 0; r < 4; ++r) {
      const int t = q0 + wave * 16 + kq * 4 + r;
      const float inv = 1.0f / l_s[r];
#pragma unroll
      for (int jd = 0; jd < 4; ++jd) {
        const int col = h * 64 + jd * 16 + mrow;
        Og[((size_t)b * 2048 + t) * 1024 + col] = f2bf(acc[jd][r] * inv);
      }
    }
  }
}

extern "C" void kernel_launch(void* const* d_in, const int* in_sizes, int n_in,
                              void* d_out, int out_size, void* d_ws, size_t ws_size,
                              hipStream_t stream) {
  const float* x = (const float*)d_in[0];
  const float* w_qkv = (const float*)d_in[1];
  const float* w_out = (const float*)d_in[2];
  const float* b_out = (const float*)d_in[3];
  float* out = (float*)d_out;

  char* ws = (char*)d_ws;
  const size_t NX = 8192ull * 1024;
  const size_t NWQ = 3072ull * 1024;
  const size_t NWO = 1024ull * 1024;
  const size_t NQ = 64ull * 2048 * 64;
  size_t off = 0;
  short* xb    = (short*)(ws + off); off += NX * 2;   // reused as Vt after gemm_qkv
  short* wqkvb = (short*)(ws + off); off += NWQ * 2;
  short* woutb = (short*)(ws + off); off += NWO * 2;
  short* q     = (short*)(ws + off); off += NQ * 2;
  short* k     = (short*)(ws + off); off += NQ * 2;
  short* v     = (short*)(ws + off); off += NQ * 2;
  short* attb  = (short*)(ws + off); off += NX * 2;
  short* vt    = xb;  // alias: xb dead after gemm_qkv
  if (off > ws_size) return;

  cast_f32_to_bf16<<<(int)(NX / 4 / 256), 256, 0, stream>>>(x, xb, (int)(NX / 4));
  cast_f32_to_bf16<<<(int)(NWQ / 4 / 256), 256, 0, stream>>>(w_qkv, wqkvb, (int)(NWQ / 4));
  cast_f32_to_bf16<<<(int)(NWO / 4 / 256), 256, 0, stream>>>(w_out, woutb, (int)(NWO / 4));
  gemm_qkv<<<dim3(24, 64), 256, 0, stream>>>(xb, wqkvb, q, k, v);
  transpose_v<<<dim3(32, 64), 256, 0, stream>>>(v, vt);
  flash_attn<<<dim3(16, 64), 256, 0, stream>>>(q, k, vt, attb);
  gemm_out<<<dim3(8, 64), 256, 0, stream>>>(attb, woutb, b_out, out);
}

// Round 4
// 279.335 us; speedup vs baseline: 2.0195x; 1.2587x over previous
//
#include <hip/hip_runtime.h>
#include <stdint.h>

// MultiHeadAttention: B=4, T=2048, C=1024, H=16, D=64, causal, scale=1/8.
// R4: flash rework — fixed-max (M=15) softmax seeded via MFMA C-init, scale
// folded into K (gemm_qkv epilogue), deferred l reduction, cheap bf16 pack,
// XOR chunk-swizzled K/Vt LDS (conflict-free reads w/ global_load_lds),
// paired q-tiles (bx,31-bx) sharing one K/V stream, double-buffered staging.
//
// MFMA 16x16x32 bf16 layouts:
//   A frag: m = lane&15, k = (lane>>4)*8 + j
//   B frag: n = lane&15, k = (lane>>4)*8 + j
//   C/D:    col = lane&15, row = (lane>>4)*4 + reg

typedef __attribute__((ext_vector_type(8))) short bf16x8;
typedef __attribute__((ext_vector_type(4))) float f32x4;

#define EXP2F(x) __builtin_amdgcn_exp2f(x)
#define SL2E 0.18033688011112042f  /* 0.125 * log2(e) */
#define FIXED_M 15.0f

__device__ __forceinline__ short f2bf(float f) {
  union { float f; unsigned u; } c; c.f = f;
  unsigned u = c.u;
  unsigned r = (u + 0x7fffu + ((u >> 16) & 1u)) >> 16;
  return (short)(unsigned short)r;
}

__device__ __forceinline__ short f2bf_fast(float f) {  // round-half-up, 2 ops
  union { float f; unsigned u; } c; c.f = f;
  return (short)(unsigned short)((c.u + 0x8000u) >> 16);
}

// async 16B global -> LDS (dest = wave-uniform base + lane*16)
__device__ __forceinline__ void llds16(const short* g, short* l) {
  __builtin_amdgcn_global_load_lds(
      (const __attribute__((address_space(1))) unsigned int*)g,
      (__attribute__((address_space(3))) unsigned int*)l, 16, 0, 0);
}

__global__ __launch_bounds__(256) void cast_f32_to_bf16(
    const float* __restrict__ src, short* __restrict__ dst, int n4) {
  int i = blockIdx.x * 256 + threadIdx.x;
  if (i >= n4) return;
  float4 f = ((const float4*)src)[i];
  short4 o;
  o.x = f2bf(f.x); o.y = f2bf(f.y); o.z = f2bf(f.z); o.w = f2bf(f.w);
  ((short4*)dst)[i] = o;
}

// V [bh][t][d=64] -> Vt [bh][d][t]. Tile 64x64 via LDS (stride 72).
__global__ __launch_bounds__(256) void transpose_v(
    const short* __restrict__ V, short* __restrict__ Vt) {
  const int T = 2048;
  __shared__ short lT[64 * 72];
  const int tid = threadIdx.x;
  const int t0 = blockIdx.x * 64;
  const int bh = blockIdx.y;
  const size_t ib = (size_t)bh * T * 64;
  const size_t ob = (size_t)bh * 64 * T;
#pragma unroll
  for (int call = 0; call < 2; ++call) {
    const int c = call * 256 + tid;
    bf16x8 vv = *(const bf16x8*)(V + ib + (size_t)(t0 + (c >> 3)) * 64 + (c & 7) * 8);
#pragma unroll
    for (int jj = 0; jj < 8; ++jj)
      lT[((c & 7) * 8 + jj) * 72 + (c >> 3)] = vv[jj];
  }
  __syncthreads();
#pragma unroll
  for (int call = 0; call < 2; ++call) {
    const int c = call * 256 + tid;
    bf16x8 o = *(const bf16x8*)&lT[(c >> 3) * 72 + (c & 7) * 8];
    *(bf16x8*)(Vt + ob + (size_t)(c >> 3) * T + t0 + (c & 7) * 8) = o;
  }
}

// ---------------------------------------------------------------------------
// GEMM (B^T): C[m,n] = sum_k A[m,k]*Bw[n,k]. 128x128 tile, BK=32,
// 4 waves 2x2, global_load_lds width-16 staging. K output pre-scaled by SL2E.
// ---------------------------------------------------------------------------
__global__ __launch_bounds__(256) void gemm_qkv(
    const short* __restrict__ A, const short* __restrict__ Bw,
    short* __restrict__ Qo, short* __restrict__ Ko, short* __restrict__ Vo) {
  const int K = 1024;
  __shared__ short lA[128 * 32];
  __shared__ short lB[128 * 32];
  const int tid = threadIdx.x;
  const int lane = tid & 63;
  const int wave = tid >> 6;
  const int m0 = blockIdx.y * 128;
  const int n0 = blockIdx.x * 128;
  const int wm = (wave >> 1) * 64;
  const int wn = (wave & 1) * 64;
  const int mrow = lane & 15;
  const int kq = lane >> 4;

  f32x4 acc[4][4];
#pragma unroll
  for (int i = 0; i < 4; ++i)
#pragma unroll
    for (int j = 0; j < 4; ++j) acc[i][j] = (f32x4){0.f, 0.f, 0.f, 0.f};

  for (int k0 = 0; k0 < K; k0 += 32) {
#pragma unroll
    for (int call = 0; call < 2; ++call) {
      const int cb = call * 256 + wave * 64;
      const int c = cb + lane;
      llds16(A + (size_t)(m0 + (c >> 2)) * K + k0 + (c & 3) * 8, &lA[cb * 8]);
      llds16(Bw + (size_t)(n0 + (c >> 2)) * K + k0 + (c & 3) * 8, &lB[cb * 8]);
    }
    __syncthreads();
    bf16x8 af[4], bfr[4];
#pragma unroll
    for (int i = 0; i < 4; ++i)
      af[i] = *(const bf16x8*)&lA[(wm + i * 16 + mrow) * 32 + kq * 8];
#pragma unroll
    for (int j = 0; j < 4; ++j)
      bfr[j] = *(const bf16x8*)&lB[(wn + j * 16 + mrow) * 32 + kq * 8];
#pragma unroll
    for (int i = 0; i < 4; ++i)
#pragma unroll
      for (int j = 0; j < 4; ++j)
        acc[i][j] = __builtin_amdgcn_mfma_f32_16x16x32_bf16(af[i], bfr[j], acc[i][j], 0, 0, 0);
    __syncthreads();
  }

#pragma unroll
  for (int i = 0; i < 4; ++i) {
    const int m = m0 + wm + i * 16 + kq * 4;
    const int b = m >> 11;
    const int t = m & 2047;
#pragma unroll
    for (int j = 0; j < 4; ++j) {
      const int o = n0 + wn + j * 16 + mrow;
      const int which = o >> 10;          // 0=q 1=k 2=v
      const int c = o & 1023;
      const int h = c >> 6;
      const int d = c & 63;
      short* dst = which == 0 ? Qo : (which == 1 ? Ko : Vo);
      const float sc_ = (which == 1) ? SL2E : 1.0f;  // fold attn scale into K
      const size_t off = ((size_t)(b * 16 + h) * 2048 + t) * 64 + d;
#pragma unroll
      for (int r = 0; r < 4; ++r)
        dst[off + (size_t)r * 64] = f2bf(acc[i][j][r] * sc_);
    }
  }
}

__global__ __launch_bounds__(256) void gemm_out(
    const short* __restrict__ A, const short* __restrict__ Bw,
    const float* __restrict__ bias, float* __restrict__ Out) {
  const int K = 1024;
  __shared__ short lA[128 * 32];
  __shared__ short lB[128 * 32];
  const int tid = threadIdx.x;
  const int lane = tid & 63;
  const int wave = tid >> 6;
  const int m0 = blockIdx.y * 128;
  const int n0 = blockIdx.x * 128;
  const int wm = (wave >> 1) * 64;
  const int wn = (wave & 1) * 64;
  const int mrow = lane & 15;
  const int kq = lane >> 4;

  f32x4 acc[4][4];
#pragma unroll
  for (int i = 0; i < 4; ++i)
#pragma unroll
    for (int j = 0; j < 4; ++j) acc[i][j] = (f32x4){0.f, 0.f, 0.f, 0.f};

  for (int k0 = 0; k0 < K; k0 += 32) {
#pragma unroll
    for (int call = 0; call < 2; ++call) {
      const int cb = call * 256 + wave * 64;
      const int c = cb + lane;
      llds16(A + (size_t)(m0 + (c >> 2)) * K + k0 + (c & 3) * 8, &lA[cb * 8]);
      llds16(Bw + (size_t)(n0 + (c >> 2)) * K + k0 + (c & 3) * 8, &lB[cb * 8]);
    }
    __syncthreads();
    bf16x8 af[4], bfr[4];
#pragma unroll
    for (int i = 0; i < 4; ++i)
      af[i] = *(const bf16x8*)&lA[(wm + i * 16 + mrow) * 32 + kq * 8];
#pragma unroll
    for (int j = 0; j < 4; ++j)
      bfr[j] = *(const bf16x8*)&lB[(wn + j * 16 + mrow) * 32 + kq * 8];
#pragma unroll
    for (int i = 0; i < 4; ++i)
#pragma unroll
      for (int j = 0; j < 4; ++j)
        acc[i][j] = __builtin_amdgcn_mfma_f32_16x16x32_bf16(af[i], bfr[j], acc[i][j], 0, 0, 0);
    __syncthreads();
  }

#pragma unroll
  for (int i = 0; i < 4; ++i) {
    const int m = m0 + wm + i * 16 + kq * 4;
#pragma unroll
    for (int j = 0; j < 4; ++j) {
      const int n = n0 + wn + j * 16 + mrow;
      const float bb = bias[n];
#pragma unroll
      for (int r = 0; r < 4; ++r)
        Out[(size_t)(m + r) * 1024 + n] = acc[i][j][r] + bb;
    }
  }
}

// ---------------------------------------------------------------------------
// Flash attention R4. Grid (16, B*H). Block handles q-tiles qtA=bx, qtB=31-bx
// sharing ONE staged K/Vt stream (kt = 0..qtB). 4 waves x 16 q-rows each.
// Fixed-max softmax (M=15, seeded via MFMA C-init); l reduced once at end.
// K/Vt LDS chunk-XOR-swizzled at staging source -> bank-uniform b128 reads.
// ---------------------------------------------------------------------------
__global__ __launch_bounds__(256) void flash_attn(
    const short* __restrict__ Qg, const short* __restrict__ Kg,
    const short* __restrict__ Vtg, short* __restrict__ Og) {
  const int T = 2048;
  __shared__ short lK[2][64 * 64];
  __shared__ short lVt[2][64 * 64];
  __shared__ short lP[4 * 16 * 76];
  const int tid = threadIdx.x;
  const int lane = tid & 63;
  const int wave = tid >> 6;
  const int bh = blockIdx.y;
  const int mrow = lane & 15;
  const int kq = lane >> 4;
  const int swz = mrow & 7;
  const size_t base = (size_t)bh * T * 64;   // Q,K: [bh][t][d]
  const size_t vbase = (size_t)bh * 64 * T;  // Vt:  [bh][d][t]
  const int qtA = blockIdx.x;        // 0..15
  const int qtB = 31 - qtA;          // 16..31

  // Q A-fragments for both segments
  bf16x8 aqA0, aqA1, aqB0, aqB1;
  {
    const short* qpA = Qg + base + (size_t)(qtA * 64 + wave * 16 + mrow) * 64 + kq * 8;
    aqA0 = *(const bf16x8*)qpA;
    aqA1 = *(const bf16x8*)(qpA + 32);
    const short* qpB = Qg + base + (size_t)(qtB * 64 + wave * 16 + mrow) * 64 + kq * 8;
    aqB0 = *(const bf16x8*)qpB;
    aqB1 = *(const bf16x8*)(qpB + 32);
  }

  f32x4 accA[4], accB[4];
  float lA4[4], lB4[4];
#pragma unroll
  for (int jd = 0; jd < 4; ++jd) {
    accA[jd] = (f32x4){0.f, 0.f, 0.f, 0.f};
    accB[jd] = (f32x4){0.f, 0.f, 0.f, 0.f};
  }
#pragma unroll
  for (int r = 0; r < 4; ++r) { lA4[r] = 0.f; lB4[r] = 0.f; }

  // stage K/Vt tile nt into buffer buf, with chunk-XOR swizzle on source col
  auto stage = [&](int nt, int buf) {
#pragma unroll
    for (int call = 0; call < 2; ++call) {
      const int cb = call * 256 + wave * 64;
      const int c = cb + lane;
      const int row = c >> 3;
      const int scol = (c & 7) ^ (row & 7);
      llds16(Kg + base + (size_t)(nt * 64 + row) * 64 + scol * 8, &lK[buf][cb * 8]);
      llds16(Vtg + vbase + (size_t)row * T + nt * 64 + scol * 8, &lVt[buf][cb * 8]);
    }
  };

  stage(0, 0);
  __syncthreads();

  for (int kt = 0; kt <= qtB; ++kt) {
    const int bcur = kt & 1;
    if (kt < qtB) stage(kt + 1, bcur ^ 1);
    const short* K_ = lK[bcur];
    const short* Vt_ = lVt[bcur];

    auto seg_compute = [&](int qt, bf16x8 aq0, bf16x8 aq1, f32x4* acc, float* l4) {
      // S = Q K'^T - M  (scale folded into K, M seeded via C)
      f32x4 sc[4];
#pragma unroll
      for (int j = 0; j < 4; ++j) {
        const short* krow = &K_[(j * 16 + mrow) * 64];
        bf16x8 kb0 = *(const bf16x8*)&krow[(kq ^ swz) * 8];
        bf16x8 kb1 = *(const bf16x8*)&krow[((4 + kq) ^ swz) * 8];
        f32x4 s = (f32x4){-FIXED_M, -FIXED_M, -FIXED_M, -FIXED_M};
        s = __builtin_amdgcn_mfma_f32_16x16x32_bf16(aq0, kb0, s, 0, 0, 0);
        s = __builtin_amdgcn_mfma_f32_16x16x32_bf16(aq1, kb1, s, 0, 0, 0);
        sc[j] = s;
      }

      if (kt == qt) {  // diagonal tile: causal mask
        const int qrow = qt * 64 + wave * 16 + kq * 4;
#pragma unroll
        for (int j = 0; j < 4; ++j) {
          const int key = kt * 64 + j * 16 + mrow;
#pragma unroll
          for (int r = 0; r < 4; ++r)
            if (key > qrow + r) sc[j][r] = -1e30f;
        }
      }

      // P = exp2(sc); accumulate l per-lane; pack to LDS (stride 76)
      short* pw = &lP[wave * 1216];
#pragma unroll
      for (int j = 0; j < 4; ++j)
#pragma unroll
        for (int r = 0; r < 4; ++r) {
          const float p = EXP2F(sc[j][r]);
          l4[r] += p;
          pw[(kq * 4 + r) * 76 + j * 16 + mrow] = f2bf_fast(p);
        }

      // PV
      bf16x8 pa0 = *(const bf16x8*)&lP[wave * 1216 + mrow * 76 + kq * 8];
      bf16x8 pa1 = *(const bf16x8*)&lP[wave * 1216 + mrow * 76 + 32 + kq * 8];
#pragma unroll
      for (int jd = 0; jd < 4; ++jd) {
        const short* vrow = &Vt_[(jd * 16 + mrow) * 64];
        bf16x8 vb0 = *(const bf16x8*)&vrow[(kq ^ swz) * 8];
        bf16x8 vb1 = *(const bf16x8*)&vrow[((4 + kq) ^ swz) * 8];
        acc[jd] = __builtin_amdgcn_mfma_f32_16x16x32_bf16(pa0, vb0, acc[jd], 0, 0, 0);
        acc[jd] = __builtin_amdgcn_mfma_f32_16x16x32_bf16(pa1, vb1, acc[jd], 0, 0, 0);
      }
    };

    if (kt <= qtA) seg_compute(qtA, aqA0, aqA1, accA, lA4);
    seg_compute(qtB, aqB0, aqB1, accB, lB4);
    __syncthreads();
  }

  // epilogue: reduce l across the 16 lanes of each quad group, write O
  const int b = bh >> 4;
  const int h = bh & 15;
#pragma unroll
  for (int off = 1; off < 16; off <<= 1)
#pragma unroll
    for (int r = 0; r < 4; ++r) {
      lA4[r] += __shfl_xor(lA4[r], off);
      lB4[r] += __shfl_xor(lB4[r], off);
    }
#pragma unroll
  for (int r = 0; r < 4; ++r) {
    const float invA = 1.0f / lA4[r];
    const float invB = 1.0f / lB4[r];
    const int tA = qtA * 64 + wave * 16 + kq * 4 + r;
    const int tB = qtB * 64 + wave * 16 + kq * 4 + r;
#pragma unroll
    for (int jd = 0; jd < 4; ++jd) {
      const int col = h * 64 + jd * 16 + mrow;
      Og[((size_t)b * 2048 + tA) * 1024 + col] = f2bf(accA[jd][r] * invA);
      Og[((size_t)b * 2048 + tB) * 1024 + col] = f2bf(accB[jd][r] * invB);
    }
  }
}

extern "C" void kernel_launch(void* const* d_in, const int* in_sizes, int n_in,
                              void* d_out, int out_size, void* d_ws, size_t ws_size,
                              hipStream_t stream) {
  const float* x = (const float*)d_in[0];
  const float* w_qkv = (const float*)d_in[1];
  const float* w_out = (const float*)d_in[2];
  const float* b_out = (const float*)d_in[3];
  float* out = (float*)d_out;

  char* ws = (char*)d_ws;
  const size_t NX = 8192ull * 1024;
  const size_t NWQ = 3072ull * 1024;
  const size_t NWO = 1024ull * 1024;
  const size_t NQ = 64ull * 2048 * 64;
  size_t off = 0;
  short* xb    = (short*)(ws + off); off += NX * 2;   // reused as Vt after gemm_qkv
  short* wqkvb = (short*)(ws + off); off += NWQ * 2;
  short* woutb = (short*)(ws + off); off += NWO * 2;
  short* q     = (short*)(ws + off); off += NQ * 2;
  short* k     = (short*)(ws + off); off += NQ * 2;
  short* v     = (short*)(ws + off); off += NQ * 2;
  short* attb  = (short*)(ws + off); off += NX * 2;
  short* vt    = xb;  // alias: xb dead after gemm_qkv
  if (off > ws_size) return;

  cast_f32_to_bf16<<<(int)(NX / 4 / 256), 256, 0, stream>>>(x, xb, (int)(NX / 4));
  cast_f32_to_bf16<<<(int)(NWQ / 4 / 256), 256, 0, stream>>>(w_qkv, wqkvb, (int)(NWQ / 4));
  cast_f32_to_bf16<<<(int)(NWO / 4 / 256), 256, 0, stream>>>(w_out, woutb, (int)(NWO / 4));
  gemm_qkv<<<dim3(24, 64), 256, 0, stream>>>(xb, wqkvb, q, k, v);
  transpose_v<<<dim3(32, 64), 256, 0, stream>>>(v, vt);
  flash_attn<<<dim3(16, 64), 256, 0, stream>>>(q, k, vt, attb);
  gemm_out<<<dim3(8, 64), 256, 0, stream>>>(attb, woutb, b_out, out);
}

// Round 5
// 270.478 us; speedup vs baseline: 2.0856x; 1.0327x over previous
//
#include <hip/hip_runtime.h>
#include <stdint.h>

// MultiHeadAttention: B=4, T=2048, C=1024, H=16, D=64, causal, scale=1/8.
// R5: flash — l via ones-MFMA (consistent with packed P), truncating bf16
// pack, XCD-swizzled grid (bh on blockIdx.x). gemm_qkv — LDS corner-turn
// epilogue with 16B coalesced stores. Everything else as R4.
//
// MFMA 16x16x32 bf16 layouts:
//   A frag: m = lane&15, k = (lane>>4)*8 + j
//   B frag: n = lane&15, k = (lane>>4)*8 + j
//   C/D:    col = lane&15, row = (lane>>4)*4 + reg

typedef __attribute__((ext_vector_type(8))) short bf16x8;
typedef __attribute__((ext_vector_type(4))) float f32x4;

#define EXP2F(x) __builtin_amdgcn_exp2f(x)
#define SL2E 0.18033688011112042f  /* 0.125 * log2(e) */
#define FIXED_M 15.0f

__device__ __forceinline__ short f2bf(float f) {
  union { float f; unsigned u; } c; c.f = f;
  unsigned u = c.u;
  unsigned r = (u + 0x7fffu + ((u >> 16) & 1u)) >> 16;
  return (short)(unsigned short)r;
}

__device__ __forceinline__ short f2bf_trunc(float f) {  // 1 op; bias cancels via l
  union { float f; unsigned u; } c; c.f = f;
  return (short)(unsigned short)(c.u >> 16);
}

// async 16B global -> LDS (dest = wave-uniform base + lane*16)
__device__ __forceinline__ void llds16(const short* g, short* l) {
  __builtin_amdgcn_global_load_lds(
      (const __attribute__((address_space(1))) unsigned int*)g,
      (__attribute__((address_space(3))) unsigned int*)l, 16, 0, 0);
}

__global__ __launch_bounds__(256) void cast_f32_to_bf16(
    const float* __restrict__ src, short* __restrict__ dst, int n4) {
  int i = blockIdx.x * 256 + threadIdx.x;
  if (i >= n4) return;
  float4 f = ((const float4*)src)[i];
  short4 o;
  o.x = f2bf(f.x); o.y = f2bf(f.y); o.z = f2bf(f.z); o.w = f2bf(f.w);
  ((short4*)dst)[i] = o;
}

// V [bh][t][d=64] -> Vt [bh][d][t]. Tile 64x64 via LDS (stride 72).
__global__ __launch_bounds__(256) void transpose_v(
    const short* __restrict__ V, short* __restrict__ Vt) {
  const int T = 2048;
  __shared__ short lT[64 * 72];
  const int tid = threadIdx.x;
  const int t0 = blockIdx.x * 64;
  const int bh = blockIdx.y;
  const size_t ib = (size_t)bh * T * 64;
  const size_t ob = (size_t)bh * 64 * T;
#pragma unroll
  for (int call = 0; call < 2; ++call) {
    const int c = call * 256 + tid;
    bf16x8 vv = *(const bf16x8*)(V + ib + (size_t)(t0 + (c >> 3)) * 64 + (c & 7) * 8);
#pragma unroll
    for (int jj = 0; jj < 8; ++jj)
      lT[((c & 7) * 8 + jj) * 72 + (c >> 3)] = vv[jj];
  }
  __syncthreads();
#pragma unroll
  for (int call = 0; call < 2; ++call) {
    const int c = call * 256 + tid;
    bf16x8 o = *(const bf16x8*)&lT[(c >> 3) * 72 + (c & 7) * 8];
    *(bf16x8*)(Vt + ob + (size_t)(c >> 3) * T + t0 + (c & 7) * 8) = o;
  }
}

// ---------------------------------------------------------------------------
// QKV GEMM (B^T): C[m,n] = sum_k A[m,k]*Bw[n,k]. 128x128 tile, BK=32,
// 4 waves 2x2, global_load_lds staging. K pre-scaled by SL2E. Epilogue:
// LDS corner-turn (stride 132) -> 16B coalesced stores to q/k/v [B,H,T,D].
// ---------------------------------------------------------------------------
__global__ __launch_bounds__(256) void gemm_qkv(
    const short* __restrict__ A, const short* __restrict__ Bw,
    short* __restrict__ Qo, short* __restrict__ Ko, short* __restrict__ Vo) {
  const int K = 1024;
  __shared__ short lA[128 * 32];
  __shared__ short lB[128 * 32];
  __shared__ short lC[128 * 132];
  const int tid = threadIdx.x;
  const int lane = tid & 63;
  const int wave = tid >> 6;
  const int m0 = blockIdx.y * 128;
  const int n0 = blockIdx.x * 128;
  const int wm = (wave >> 1) * 64;
  const int wn = (wave & 1) * 64;
  const int mrow = lane & 15;
  const int kq = lane >> 4;

  f32x4 acc[4][4];
#pragma unroll
  for (int i = 0; i < 4; ++i)
#pragma unroll
    for (int j = 0; j < 4; ++j) acc[i][j] = (f32x4){0.f, 0.f, 0.f, 0.f};

  for (int k0 = 0; k0 < K; k0 += 32) {
#pragma unroll
    for (int call = 0; call < 2; ++call) {
      const int cb = call * 256 + wave * 64;
      const int c = cb + lane;
      llds16(A + (size_t)(m0 + (c >> 2)) * K + k0 + (c & 3) * 8, &lA[cb * 8]);
      llds16(Bw + (size_t)(n0 + (c >> 2)) * K + k0 + (c & 3) * 8, &lB[cb * 8]);
    }
    __syncthreads();
    bf16x8 af[4], bfr[4];
#pragma unroll
    for (int i = 0; i < 4; ++i)
      af[i] = *(const bf16x8*)&lA[(wm + i * 16 + mrow) * 32 + kq * 8];
#pragma unroll
    for (int j = 0; j < 4; ++j)
      bfr[j] = *(const bf16x8*)&lB[(wn + j * 16 + mrow) * 32 + kq * 8];
#pragma unroll
    for (int i = 0; i < 4; ++i)
#pragma unroll
      for (int j = 0; j < 4; ++j)
        acc[i][j] = __builtin_amdgcn_mfma_f32_16x16x32_bf16(af[i], bfr[j], acc[i][j], 0, 0, 0);
    __syncthreads();
  }

  // corner-turn: dump acc (bf16, K-scaled) into lC[row][col], stride 132
#pragma unroll
  for (int i = 0; i < 4; ++i) {
    const int row = wm + i * 16 + kq * 4;
#pragma unroll
    for (int j = 0; j < 4; ++j) {
      const int col = wn + j * 16 + mrow;
      const float sc_ = (((n0 + col) >> 10) == 1) ? SL2E : 1.0f;
#pragma unroll
      for (int r = 0; r < 4; ++r)
        lC[(row + r) * 132 + col] = f2bf(acc[i][j][r] * sc_);
    }
  }
  __syncthreads();

  // 2048 chunks of 8 shorts: chunk cc -> row=cc>>4, 8-col group cc&15
#pragma unroll
  for (int call = 0; call < 8; ++call) {
    const int cc = call * 256 + tid;
    const int row = cc >> 4;
    const int m = m0 + row;
    const int b = m >> 11;
    const int t = m & 2047;
    const int o = n0 + (cc & 15) * 8;
    const int which = o >> 10;          // 0=q 1=k 2=v
    const int c = o & 1023;
    const int h = c >> 6;
    const int d = c & 63;
    short* dst = which == 0 ? Qo : (which == 1 ? Ko : Vo);
    bf16x8 val = *(const bf16x8*)&lC[row * 132 + (cc & 15) * 8];
    *(bf16x8*)(dst + ((size_t)(b * 16 + h) * 2048 + t) * 64 + d) = val;
  }
}

__global__ __launch_bounds__(256) void gemm_out(
    const short* __restrict__ A, const short* __restrict__ Bw,
    const float* __restrict__ bias, float* __restrict__ Out) {
  const int K = 1024;
  __shared__ short lA[128 * 32];
  __shared__ short lB[128 * 32];
  const int tid = threadIdx.x;
  const int lane = tid & 63;
  const int wave = tid >> 6;
  const int m0 = blockIdx.y * 128;
  const int n0 = blockIdx.x * 128;
  const int wm = (wave >> 1) * 64;
  const int wn = (wave & 1) * 64;
  const int mrow = lane & 15;
  const int kq = lane >> 4;

  f32x4 acc[4][4];
#pragma unroll
  for (int i = 0; i < 4; ++i)
#pragma unroll
    for (int j = 0; j < 4; ++j) acc[i][j] = (f32x4){0.f, 0.f, 0.f, 0.f};

  for (int k0 = 0; k0 < K; k0 += 32) {
#pragma unroll
    for (int call = 0; call < 2; ++call) {
      const int cb = call * 256 + wave * 64;
      const int c = cb + lane;
      llds16(A + (size_t)(m0 + (c >> 2)) * K + k0 + (c & 3) * 8, &lA[cb * 8]);
      llds16(Bw + (size_t)(n0 + (c >> 2)) * K + k0 + (c & 3) * 8, &lB[cb * 8]);
    }
    __syncthreads();
    bf16x8 af[4], bfr[4];
#pragma unroll
    for (int i = 0; i < 4; ++i)
      af[i] = *(const bf16x8*)&lA[(wm + i * 16 + mrow) * 32 + kq * 8];
#pragma unroll
    for (int j = 0; j < 4; ++j)
      bfr[j] = *(const bf16x8*)&lB[(wn + j * 16 + mrow) * 32 + kq * 8];
#pragma unroll
    for (int i = 0; i < 4; ++i)
#pragma unroll
      for (int j = 0; j < 4; ++j)
        acc[i][j] = __builtin_amdgcn_mfma_f32_16x16x32_bf16(af[i], bfr[j], acc[i][j], 0, 0, 0);
    __syncthreads();
  }

#pragma unroll
  for (int i = 0; i < 4; ++i) {
    const int m = m0 + wm + i * 16 + kq * 4;
#pragma unroll
    for (int j = 0; j < 4; ++j) {
      const int n = n0 + wn + j * 16 + mrow;
      const float bb = bias[n];
#pragma unroll
      for (int r = 0; r < 4; ++r)
        Out[(size_t)(m + r) * 1024 + n] = acc[i][j][r] + bb;
    }
  }
}

// ---------------------------------------------------------------------------
// Flash attention R5. Grid (64 bh, 16 pair): all blocks of one bh share an
// XCD (id%8 = bh%8) -> K/Vt L2-resident. Block handles q-tiles qtA=by,
// qtB=31-by sharing one staged K/Vt stream. Fixed-max softmax (M=15 via
// MFMA C-init); l via ones-MFMA over packed P (pack bias cancels);
// truncating bf16 pack; XOR chunk-swizzled K/Vt LDS; double-buffered.
// ---------------------------------------------------------------------------
__global__ __launch_bounds__(256) void flash_attn(
    const short* __restrict__ Qg, const short* __restrict__ Kg,
    const short* __restrict__ Vtg, short* __restrict__ Og) {
  const int T = 2048;
  __shared__ short lK[2][64 * 64];
  __shared__ short lVt[2][64 * 64];
  __shared__ short lP[4 * 16 * 76];
  const int tid = threadIdx.x;
  const int lane = tid & 63;
  const int wave = tid >> 6;
  const int bh = blockIdx.x;
  const int mrow = lane & 15;
  const int kq = lane >> 4;
  const int swz = mrow & 7;
  const size_t base = (size_t)bh * T * 64;   // Q,K: [bh][t][d]
  const size_t vbase = (size_t)bh * 64 * T;  // Vt:  [bh][d][t]
  const int qtA = blockIdx.y;        // 0..15
  const int qtB = 31 - qtA;          // 16..31

  const bf16x8 ones = {0x3F80, 0x3F80, 0x3F80, 0x3F80, 0x3F80, 0x3F80, 0x3F80, 0x3F80};

  bf16x8 aqA0, aqA1, aqB0, aqB1;
  {
    const short* qpA = Qg + base + (size_t)(qtA * 64 + wave * 16 + mrow) * 64 + kq * 8;
    aqA0 = *(const bf16x8*)qpA;
    aqA1 = *(const bf16x8*)(qpA + 32);
    const short* qpB = Qg + base + (size_t)(qtB * 64 + wave * 16 + mrow) * 64 + kq * 8;
    aqB0 = *(const bf16x8*)qpB;
    aqB1 = *(const bf16x8*)(qpB + 32);
  }

  f32x4 accA[4], accB[4], lacA, lacB;
#pragma unroll
  for (int jd = 0; jd < 4; ++jd) {
    accA[jd] = (f32x4){0.f, 0.f, 0.f, 0.f};
    accB[jd] = (f32x4){0.f, 0.f, 0.f, 0.f};
  }
  lacA = (f32x4){0.f, 0.f, 0.f, 0.f};
  lacB = (f32x4){0.f, 0.f, 0.f, 0.f};

  auto stage = [&](int nt, int buf) {
#pragma unroll
    for (int call = 0; call < 2; ++call) {
      const int cb = call * 256 + wave * 64;
      const int c = cb + lane;
      const int row = c >> 3;
      const int scol = (c & 7) ^ (row & 7);
      llds16(Kg + base + (size_t)(nt * 64 + row) * 64 + scol * 8, &lK[buf][cb * 8]);
      llds16(Vtg + vbase + (size_t)row * T + nt * 64 + scol * 8, &lVt[buf][cb * 8]);
    }
  };

  stage(0, 0);
  __syncthreads();

  for (int kt = 0; kt <= qtB; ++kt) {
    const int bcur = kt & 1;
    if (kt < qtB) stage(kt + 1, bcur ^ 1);
    const short* K_ = lK[bcur];
    const short* Vt_ = lVt[bcur];

    auto seg_compute = [&](int qt, bf16x8 aq0, bf16x8 aq1, f32x4* acc, f32x4& lac) {
      f32x4 sc[4];
#pragma unroll
      for (int j = 0; j < 4; ++j) {
        const short* krow = &K_[(j * 16 + mrow) * 64];
        bf16x8 kb0 = *(const bf16x8*)&krow[(kq ^ swz) * 8];
        bf16x8 kb1 = *(const bf16x8*)&krow[((4 + kq) ^ swz) * 8];
        f32x4 s = (f32x4){-FIXED_M, -FIXED_M, -FIXED_M, -FIXED_M};
        s = __builtin_amdgcn_mfma_f32_16x16x32_bf16(aq0, kb0, s, 0, 0, 0);
        s = __builtin_amdgcn_mfma_f32_16x16x32_bf16(aq1, kb1, s, 0, 0, 0);
        sc[j] = s;
      }

      if (kt == qt) {  // diagonal tile: causal mask
        const int qrow = qt * 64 + wave * 16 + kq * 4;
#pragma unroll
        for (int j = 0; j < 4; ++j) {
          const int key = kt * 64 + j * 16 + mrow;
#pragma unroll
          for (int r = 0; r < 4; ++r)
            if (key > qrow + r) sc[j][r] = -1e30f;
        }
      }

      // P = exp2(sc); truncate-pack to LDS (stride 76)
      short* pw = &lP[wave * 1216];
#pragma unroll
      for (int j = 0; j < 4; ++j)
#pragma unroll
        for (int r = 0; r < 4; ++r)
          pw[(kq * 4 + r) * 76 + j * 16 + mrow] = f2bf_trunc(EXP2F(sc[j][r]));

      // PV + l (l = packed-P . ones via MFMA; consistent normalization)
      bf16x8 pa0 = *(const bf16x8*)&lP[wave * 1216 + mrow * 76 + kq * 8];
      bf16x8 pa1 = *(const bf16x8*)&lP[wave * 1216 + mrow * 76 + 32 + kq * 8];
      lac = __builtin_amdgcn_mfma_f32_16x16x32_bf16(pa0, ones, lac, 0, 0, 0);
      lac = __builtin_amdgcn_mfma_f32_16x16x32_bf16(pa1, ones, lac, 0, 0, 0);
#pragma unroll
      for (int jd = 0; jd < 4; ++jd) {
        const short* vrow = &Vt_[(jd * 16 + mrow) * 64];
        bf16x8 vb0 = *(const bf16x8*)&vrow[(kq ^ swz) * 8];
        bf16x8 vb1 = *(const bf16x8*)&vrow[((4 + kq) ^ swz) * 8];
        acc[jd] = __builtin_amdgcn_mfma_f32_16x16x32_bf16(pa0, vb0, acc[jd], 0, 0, 0);
        acc[jd] = __builtin_amdgcn_mfma_f32_16x16x32_bf16(pa1, vb1, acc[jd], 0, 0, 0);
      }
    };

    if (kt <= qtA) seg_compute(qtA, aqA0, aqA1, accA, lacA);
    seg_compute(qtB, aqB0, aqB1, accB, lacB);
    __syncthreads();
  }

  // epilogue: l already per-row in lac (col-independent); write O
  const int b = bh >> 4;
  const int h = bh & 15;
#pragma unroll
  for (int r = 0; r < 4; ++r) {
    const float invA = 1.0f / lacA[r];
    const float invB = 1.0f / lacB[r];
    const int tA = qtA * 64 + wave * 16 + kq * 4 + r;
    const int tB = qtB * 64 + wave * 16 + kq * 4 + r;
#pragma unroll
    for (int jd = 0; jd < 4; ++jd) {
      const int col = h * 64 + jd * 16 + mrow;
      Og[((size_t)b * 2048 + tA) * 1024 + col] = f2bf(accA[jd][r] * invA);
      Og[((size_t)b * 2048 + tB) * 1024 + col] = f2bf(accB[jd][r] * invB);
    }
  }
}

extern "C" void kernel_launch(void* const* d_in, const int* in_sizes, int n_in,
                              void* d_out, int out_size, void* d_ws, size_t ws_size,
                              hipStream_t stream) {
  const float* x = (const float*)d_in[0];
  const float* w_qkv = (const float*)d_in[1];
  const float* w_out = (const float*)d_in[2];
  const float* b_out = (const float*)d_in[3];
  float* out = (float*)d_out;

  char* ws = (char*)d_ws;
  const size_t NX = 8192ull * 1024;
  const size_t NWQ = 3072ull * 1024;
  const size_t NWO = 1024ull * 1024;
  const size_t NQ = 64ull * 2048 * 64;
  size_t off = 0;
  short* xb    = (short*)(ws + off); off += NX * 2;   // reused as Vt after gemm_qkv
  short* wqkvb = (short*)(ws + off); off += NWQ * 2;
  short* woutb = (short*)(ws + off); off += NWO * 2;
  short* q     = (short*)(ws + off); off += NQ * 2;
  short* k     = (short*)(ws + off); off += NQ * 2;
  short* v     = (short*)(ws + off); off += NQ * 2;
  short* attb  = (short*)(ws + off); off += NX * 2;
  short* vt    = xb;  // alias: xb dead after gemm_qkv
  if (off > ws_size) return;

  cast_f32_to_bf16<<<(int)(NX / 4 / 256), 256, 0, stream>>>(x, xb, (int)(NX / 4));
  cast_f32_to_bf16<<<(int)(NWQ / 4 / 256), 256, 0, stream>>>(w_qkv, wqkvb, (int)(NWQ / 4));
  cast_f32_to_bf16<<<(int)(NWO / 4 / 256), 256, 0, stream>>>(w_out, woutb, (int)(NWO / 4));
  gemm_qkv<<<dim3(24, 64), 256, 0, stream>>>(xb, wqkvb, q, k, v);
  transpose_v<<<dim3(32, 64), 256, 0, stream>>>(v, vt);
  flash_attn<<<dim3(64, 16), 256, 0, stream>>>(q, k, vt, attb);
  gemm_out<<<dim3(8, 64), 256, 0, stream>>>(attb, woutb, b_out, out);
}

// Round 7
// 262.668 us; speedup vs baseline: 2.1476x; 1.0297x over previous
//
#include <hip/hip_runtime.h>
#include <stdint.h>

// MultiHeadAttention: B=4, T=2048, C=1024, H=16, D=64, causal, scale=1/8.
// R7 = R6 with one-line fix: V-epilogue t = (m0 & 2047) + tg*8 (batch offset
// was double-counted, poisoning Vt for b>=1).
// R6: GEMMs -> BK=64, XOR-swizzled staging (conflict-free ds_read_b128),
// LDS union (staging|corner-turn), V-transpose fused into gemm_qkv.
// Flash unchanged from R5 (fixed-max softmax, l via ones-MFMA, XCD grid).
//
// MFMA 16x16x32 bf16 layouts:
//   A frag: m = lane&15, k = (lane>>4)*8 + j
//   B frag: n = lane&15, k = (lane>>4)*8 + j
//   C/D:    col = lane&15, row = (lane>>4)*4 + reg

typedef __attribute__((ext_vector_type(8))) short bf16x8;
typedef __attribute__((ext_vector_type(4))) float f32x4;

#define EXP2F(x) __builtin_amdgcn_exp2f(x)
#define SL2E 0.18033688011112042f  /* 0.125 * log2(e) */
#define FIXED_M 15.0f

__device__ __forceinline__ short f2bf(float f) {
  union { float f; unsigned u; } c; c.f = f;
  unsigned u = c.u;
  unsigned r = (u + 0x7fffu + ((u >> 16) & 1u)) >> 16;
  return (short)(unsigned short)r;
}

__device__ __forceinline__ short f2bf_trunc(float f) {  // 1 op; bias cancels via l
  union { float f; unsigned u; } c; c.f = f;
  return (short)(unsigned short)(c.u >> 16);
}

// async 16B global -> LDS (dest = wave-uniform base + lane*16)
__device__ __forceinline__ void llds16(const short* g, short* l) {
  __builtin_amdgcn_global_load_lds(
      (const __attribute__((address_space(1))) unsigned int*)g,
      (__attribute__((address_space(3))) unsigned int*)l, 16, 0, 0);
}

__global__ __launch_bounds__(256) void cast_f32_to_bf16(
    const float* __restrict__ src, short* __restrict__ dst, int n4) {
  int i = blockIdx.x * 256 + threadIdx.x;
  if (i >= n4) return;
  float4 f = ((const float4*)src)[i];
  short4 o;
  o.x = f2bf(f.x); o.y = f2bf(f.y); o.z = f2bf(f.z); o.w = f2bf(f.w);
  ((short4*)dst)[i] = o;
}

// ---------------------------------------------------------------------------
// QKV GEMM (B^T): C[m,n] = sum_k A[m,k]*Bw[n,k]. 128x128 tile, BK=64,
// 4 waves 2x2, XOR-swizzled global_load_lds staging, LDS union with
// corner-turn epilogue. Q/K blocks: row-major lC -> [B,H,T,D] stores
// (K pre-scaled by SL2E). V blocks (n0>=2048): transposed lCt -> Vt [bh][d][t].
// ---------------------------------------------------------------------------
__global__ __launch_bounds__(256) void gemm_qkv(
    const short* __restrict__ A, const short* __restrict__ Bw,
    short* __restrict__ Qo, short* __restrict__ Ko, short* __restrict__ Vt) {
  const int K = 1024;
  __shared__ short smem[17408];  // max(2*8192 staging, 128*136 lCt)
  short* lA = smem;              // [128][64]
  short* lB = smem + 8192;       // [128][64]
  const int tid = threadIdx.x;
  const int lane = tid & 63;
  const int wave = tid >> 6;
  const int m0 = blockIdx.y * 128;
  const int n0 = blockIdx.x * 128;
  const int wm = (wave >> 1) * 64;
  const int wn = (wave & 1) * 64;
  const int mrow = lane & 15;
  const int kq = lane >> 4;

  f32x4 acc[4][4];
#pragma unroll
  for (int i = 0; i < 4; ++i)
#pragma unroll
    for (int j = 0; j < 4; ++j) acc[i][j] = (f32x4){0.f, 0.f, 0.f, 0.f};

  for (int k0 = 0; k0 < K; k0 += 64) {
#pragma unroll
    for (int call = 0; call < 4; ++call) {
      const int cb = call * 256 + wave * 64;
      const int c = cb + lane;
      const int row = c >> 3;
      const int scol = (c & 7) ^ (row & 7);
      llds16(A + (size_t)(m0 + row) * K + k0 + scol * 8, &lA[cb * 8]);
      llds16(Bw + (size_t)(n0 + row) * K + k0 + scol * 8, &lB[cb * 8]);
    }
    __syncthreads();
#pragma unroll
    for (int kk = 0; kk < 2; ++kk) {
      bf16x8 af[4], bfr[4];
#pragma unroll
      for (int i = 0; i < 4; ++i) {
        const int row = wm + i * 16 + mrow;
        af[i] = *(const bf16x8*)&lA[row * 64 + (((kk * 4 + kq) ^ (row & 7)) * 8)];
      }
#pragma unroll
      for (int j = 0; j < 4; ++j) {
        const int row = wn + j * 16 + mrow;
        bfr[j] = *(const bf16x8*)&lB[row * 64 + (((kk * 4 + kq) ^ (row & 7)) * 8)];
      }
#pragma unroll
      for (int i = 0; i < 4; ++i)
#pragma unroll
        for (int j = 0; j < 4; ++j)
          acc[i][j] = __builtin_amdgcn_mfma_f32_16x16x32_bf16(af[i], bfr[j], acc[i][j], 0, 0, 0);
    }
    __syncthreads();
  }

  const int b = m0 >> 11;            // whole tile lies in one batch
  if (n0 < 2048) {
    // Q/K block: row-major corner-turn (stride 132), coalesced 16B stores
    short* lC = smem;
#pragma unroll
    for (int i = 0; i < 4; ++i) {
      const int row = wm + i * 16 + kq * 4;
#pragma unroll
      for (int j = 0; j < 4; ++j) {
        const int col = wn + j * 16 + mrow;
        const float sc_ = (((n0 + col) >> 10) == 1) ? SL2E : 1.0f;
#pragma unroll
        for (int r = 0; r < 4; ++r)
          lC[(row + r) * 132 + col] = f2bf(acc[i][j][r] * sc_);
      }
    }
    __syncthreads();
#pragma unroll
    for (int call = 0; call < 8; ++call) {
      const int cc = call * 256 + tid;
      const int row = cc >> 4;
      const int t = (m0 + row) & 2047;
      const int o = n0 + (cc & 15) * 8;
      const int c = o & 1023;
      const int h = c >> 6;
      const int d = c & 63;
      short* dst = (o >> 10) == 0 ? Qo : Ko;
      bf16x8 val = *(const bf16x8*)&lC[row * 132 + (cc & 15) * 8];
      *(bf16x8*)(dst + ((size_t)(b * 16 + h) * 2048 + t) * 64 + d) = val;
    }
  } else {
    // V block: transposed corner-turn (lCt[col][row], stride 136) -> Vt [bh][d][t]
    short* lCt = smem;
#pragma unroll
    for (int i = 0; i < 4; ++i) {
      const int row = wm + i * 16 + kq * 4;
#pragma unroll
      for (int j = 0; j < 4; ++j) {
        const int col = wn + j * 16 + mrow;
#pragma unroll
        for (int r = 0; r < 4; ++r)
          lCt[col * 136 + row + r] = f2bf(acc[i][j][r]);
      }
    }
    __syncthreads();
#pragma unroll
    for (int call = 0; call < 8; ++call) {
      const int cc = call * 256 + tid;
      const int col = cc >> 4;
      const int tg = cc & 15;
      const int o = n0 + col;           // 2048..3071
      const int d = o & 63;
      const int h = (o >> 6) & 15;
      const int t = (m0 & 2047) + tg * 8;   // FIX: batch offset lives in bh, not t
      bf16x8 val = *(const bf16x8*)&lCt[col * 136 + tg * 8];
      *(bf16x8*)(Vt + ((size_t)(b * 16 + h) * 64 + d) * 2048 + t) = val;
    }
  }
}

// Out-proj GEMM: M=8192, N=1024, BK=64, swizzled staging, + bias, fp32 out.
__global__ __launch_bounds__(256) void gemm_out(
    const short* __restrict__ A, const short* __restrict__ Bw,
    const float* __restrict__ bias, float* __restrict__ Out) {
  const int K = 1024;
  __shared__ short lA[128 * 64];
  __shared__ short lB[128 * 64];
  const int tid = threadIdx.x;
  const int lane = tid & 63;
  const int wave = tid >> 6;
  const int m0 = blockIdx.y * 128;
  const int n0 = blockIdx.x * 128;
  const int wm = (wave >> 1) * 64;
  const int wn = (wave & 1) * 64;
  const int mrow = lane & 15;
  const int kq = lane >> 4;

  f32x4 acc[4][4];
#pragma unroll
  for (int i = 0; i < 4; ++i)
#pragma unroll
    for (int j = 0; j < 4; ++j) acc[i][j] = (f32x4){0.f, 0.f, 0.f, 0.f};

  for (int k0 = 0; k0 < K; k0 += 64) {
#pragma unroll
    for (int call = 0; call < 4; ++call) {
      const int cb = call * 256 + wave * 64;
      const int c = cb + lane;
      const int row = c >> 3;
      const int scol = (c & 7) ^ (row & 7);
      llds16(A + (size_t)(m0 + row) * K + k0 + scol * 8, &lA[cb * 8]);
      llds16(Bw + (size_t)(n0 + row) * K + k0 + scol * 8, &lB[cb * 8]);
    }
    __syncthreads();
#pragma unroll
    for (int kk = 0; kk < 2; ++kk) {
      bf16x8 af[4], bfr[4];
#pragma unroll
      for (int i = 0; i < 4; ++i) {
        const int row = wm + i * 16 + mrow;
        af[i] = *(const bf16x8*)&lA[row * 64 + (((kk * 4 + kq) ^ (row & 7)) * 8)];
      }
#pragma unroll
      for (int j = 0; j < 4; ++j) {
        const int row = wn + j * 16 + mrow;
        bfr[j] = *(const bf16x8*)&lB[row * 64 + (((kk * 4 + kq) ^ (row & 7)) * 8)];
      }
#pragma unroll
      for (int i = 0; i < 4; ++i)
#pragma unroll
        for (int j = 0; j < 4; ++j)
          acc[i][j] = __builtin_amdgcn_mfma_f32_16x16x32_bf16(af[i], bfr[j], acc[i][j], 0, 0, 0);
    }
    __syncthreads();
  }

#pragma unroll
  for (int i = 0; i < 4; ++i) {
    const int m = m0 + wm + i * 16 + kq * 4;
#pragma unroll
    for (int j = 0; j < 4; ++j) {
      const int n = n0 + wn + j * 16 + mrow;
      const float bb = bias[n];
#pragma unroll
      for (int r = 0; r < 4; ++r)
        Out[(size_t)(m + r) * 1024 + n] = acc[i][j][r] + bb;
    }
  }
}

// ---------------------------------------------------------------------------
// Flash attention (R5 design, unchanged). Grid (64 bh, 16 pair).
// ---------------------------------------------------------------------------
__global__ __launch_bounds__(256) void flash_attn(
    const short* __restrict__ Qg, const short* __restrict__ Kg,
    const short* __restrict__ Vtg, short* __restrict__ Og) {
  const int T = 2048;
  __shared__ short lK[2][64 * 64];
  __shared__ short lVt[2][64 * 64];
  __shared__ short lP[4 * 16 * 76];
  const int tid = threadIdx.x;
  const int lane = tid & 63;
  const int wave = tid >> 6;
  const int bh = blockIdx.x;
  const int mrow = lane & 15;
  const int kq = lane >> 4;
  const int swz = mrow & 7;
  const size_t base = (size_t)bh * T * 64;   // Q,K: [bh][t][d]
  const size_t vbase = (size_t)bh * 64 * T;  // Vt:  [bh][d][t]
  const int qtA = blockIdx.y;        // 0..15
  const int qtB = 31 - qtA;          // 16..31

  const bf16x8 ones = {0x3F80, 0x3F80, 0x3F80, 0x3F80, 0x3F80, 0x3F80, 0x3F80, 0x3F80};

  bf16x8 aqA0, aqA1, aqB0, aqB1;
  {
    const short* qpA = Qg + base + (size_t)(qtA * 64 + wave * 16 + mrow) * 64 + kq * 8;
    aqA0 = *(const bf16x8*)qpA;
    aqA1 = *(const bf16x8*)(qpA + 32);
    const short* qpB = Qg + base + (size_t)(qtB * 64 + wave * 16 + mrow) * 64 + kq * 8;
    aqB0 = *(const bf16x8*)qpB;
    aqB1 = *(const bf16x8*)(qpB + 32);
  }

  f32x4 accA[4], accB[4], lacA, lacB;
#pragma unroll
  for (int jd = 0; jd < 4; ++jd) {
    accA[jd] = (f32x4){0.f, 0.f, 0.f, 0.f};
    accB[jd] = (f32x4){0.f, 0.f, 0.f, 0.f};
  }
  lacA = (f32x4){0.f, 0.f, 0.f, 0.f};
  lacB = (f32x4){0.f, 0.f, 0.f, 0.f};

  auto stage = [&](int nt, int buf) {
#pragma unroll
    for (int call = 0; call < 2; ++call) {
      const int cb = call * 256 + wave * 64;
      const int c = cb + lane;
      const int row = c >> 3;
      const int scol = (c & 7) ^ (row & 7);
      llds16(Kg + base + (size_t)(nt * 64 + row) * 64 + scol * 8, &lK[buf][cb * 8]);
      llds16(Vtg + vbase + (size_t)row * T + nt * 64 + scol * 8, &lVt[buf][cb * 8]);
    }
  };

  stage(0, 0);
  __syncthreads();

  for (int kt = 0; kt <= qtB; ++kt) {
    const int bcur = kt & 1;
    if (kt < qtB) stage(kt + 1, bcur ^ 1);
    const short* K_ = lK[bcur];
    const short* Vt_ = lVt[bcur];

    auto seg_compute = [&](int qt, bf16x8 aq0, bf16x8 aq1, f32x4* acc, f32x4& lac) {
      f32x4 sc[4];
#pragma unroll
      for (int j = 0; j < 4; ++j) {
        const short* krow = &K_[(j * 16 + mrow) * 64];
        bf16x8 kb0 = *(const bf16x8*)&krow[(kq ^ swz) * 8];
        bf16x8 kb1 = *(const bf16x8*)&krow[((4 + kq) ^ swz) * 8];
        f32x4 s = (f32x4){-FIXED_M, -FIXED_M, -FIXED_M, -FIXED_M};
        s = __builtin_amdgcn_mfma_f32_16x16x32_bf16(aq0, kb0, s, 0, 0, 0);
        s = __builtin_amdgcn_mfma_f32_16x16x32_bf16(aq1, kb1, s, 0, 0, 0);
        sc[j] = s;
      }

      if (kt == qt) {  // diagonal tile: causal mask
        const int qrow = qt * 64 + wave * 16 + kq * 4;
#pragma unroll
        for (int j = 0; j < 4; ++j) {
          const int key = kt * 64 + j * 16 + mrow;
#pragma unroll
          for (int r = 0; r < 4; ++r)
            if (key > qrow + r) sc[j][r] = -1e30f;
        }
      }

      // P = exp2(sc); truncate-pack to LDS (stride 76)
      short* pw = &lP[wave * 1216];
#pragma unroll
      for (int j = 0; j < 4; ++j)
#pragma unroll
        for (int r = 0; r < 4; ++r)
          pw[(kq * 4 + r) * 76 + j * 16 + mrow] = f2bf_trunc(EXP2F(sc[j][r]));

      // PV + l (l = packed-P . ones via MFMA; consistent normalization)
      bf16x8 pa0 = *(const bf16x8*)&lP[wave * 1216 + mrow * 76 + kq * 8];
      bf16x8 pa1 = *(const bf16x8*)&lP[wave * 1216 + mrow * 76 + 32 + kq * 8];
      lac = __builtin_amdgcn_mfma_f32_16x16x32_bf16(pa0, ones, lac, 0, 0, 0);
      lac = __builtin_amdgcn_mfma_f32_16x16x32_bf16(pa1, ones, lac, 0, 0, 0);
#pragma unroll
      for (int jd = 0; jd < 4; ++jd) {
        const short* vrow = &Vt_[(jd * 16 + mrow) * 64];
        bf16x8 vb0 = *(const bf16x8*)&vrow[(kq ^ swz) * 8];
        bf16x8 vb1 = *(const bf16x8*)&vrow[((4 + kq) ^ swz) * 8];
        acc[jd] = __builtin_amdgcn_mfma_f32_16x16x32_bf16(pa0, vb0, acc[jd], 0, 0, 0);
        acc[jd] = __builtin_amdgcn_mfma_f32_16x16x32_bf16(pa1, vb1, acc[jd], 0, 0, 0);
      }
    };

    if (kt <= qtA) seg_compute(qtA, aqA0, aqA1, accA, lacA);
    seg_compute(qtB, aqB0, aqB1, accB, lacB);
    __syncthreads();
  }

  const int b = bh >> 4;
  const int h = bh & 15;
#pragma unroll
  for (int r = 0; r < 4; ++r) {
    const float invA = 1.0f / lacA[r];
    const float invB = 1.0f / lacB[r];
    const int tA = qtA * 64 + wave * 16 + kq * 4 + r;
    const int tB = qtB * 64 + wave * 16 + kq * 4 + r;
#pragma unroll
    for (int jd = 0; jd < 4; ++jd) {
      const int col = h * 64 + jd * 16 + mrow;
      Og[((size_t)b * 2048 + tA) * 1024 + col] = f2bf(accA[jd][r] * invA);
      Og[((size_t)b * 2048 + tB) * 1024 + col] = f2bf(accB[jd][r] * invB);
    }
  }
}

extern "C" void kernel_launch(void* const* d_in, const int* in_sizes, int n_in,
                              void* d_out, int out_size, void* d_ws, size_t ws_size,
                              hipStream_t stream) {
  const float* x = (const float*)d_in[0];
  const float* w_qkv = (const float*)d_in[1];
  const float* w_out = (const float*)d_in[2];
  const float* b_out = (const float*)d_in[3];
  float* out = (float*)d_out;

  char* ws = (char*)d_ws;
  const size_t NX = 8192ull * 1024;
  const size_t NWQ = 3072ull * 1024;
  const size_t NWO = 1024ull * 1024;
  const size_t NQ = 64ull * 2048 * 64;
  size_t off = 0;
  short* xb    = (short*)(ws + off); off += NX * 2;
  short* wqkvb = (short*)(ws + off); off += NWQ * 2;
  short* woutb = (short*)(ws + off); off += NWO * 2;
  short* q     = (short*)(ws + off); off += NQ * 2;
  short* k     = (short*)(ws + off); off += NQ * 2;
  short* vt    = (short*)(ws + off); off += NQ * 2;  // V stored transposed [bh][d][t]
  short* attb  = (short*)(ws + off); off += NX * 2;
  if (off > ws_size) return;

  cast_f32_to_bf16<<<(int)(NX / 4 / 256), 256, 0, stream>>>(x, xb, (int)(NX / 4));
  cast_f32_to_bf16<<<(int)(NWQ / 4 / 256), 256, 0, stream>>>(w_qkv, wqkvb, (int)(NWQ / 4));
  cast_f32_to_bf16<<<(int)(NWO / 4 / 256), 256, 0, stream>>>(w_out, woutb, (int)(NWO / 4));
  gemm_qkv<<<dim3(24, 64), 256, 0, stream>>>(xb, wqkvb, q, k, vt);
  flash_attn<<<dim3(64, 16), 256, 0, stream>>>(q, k, vt, attb);
  gemm_out<<<dim3(8, 64), 256, 0, stream>>>(attb, woutb, b_out, out);
}

// Round 8
// 261.575 us; speedup vs baseline: 2.1566x; 1.0042x over previous
//
#include <hip/hip_runtime.h>
#include <stdint.h>

// MultiHeadAttention: B=4, T=2048, C=1024, H=16, D=64, causal, scale=1/8.
// R8: GEMMs -> double-buffered global_load_lds, ONE barrier/iter (prefetch
// k+1 while computing k), BK=32; qkv LDS union keeps 4 blocks/CU.
// Flash -> 4 q-tiles per block ({bx,31-bx,15-bx,16+bx}), grid (64,8),
// one K/V stream feeds 4 consumers (staged tiles -42%), one round at 2/CU.
//
// MFMA 16x16x32 bf16 layouts:
//   A frag: m = lane&15, k = (lane>>4)*8 + j
//   B frag: n = lane&15, k = (lane>>4)*8 + j
//   C/D:    col = lane&15, row = (lane>>4)*4 + reg

typedef __attribute__((ext_vector_type(8))) short bf16x8;
typedef __attribute__((ext_vector_type(4))) float f32x4;

#define EXP2F(x) __builtin_amdgcn_exp2f(x)
#define SL2E 0.18033688011112042f  /* 0.125 * log2(e) */
#define FIXED_M 15.0f

__device__ __forceinline__ short f2bf(float f) {
  union { float f; unsigned u; } c; c.f = f;
  unsigned u = c.u;
  unsigned r = (u + 0x7fffu + ((u >> 16) & 1u)) >> 16;
  return (short)(unsigned short)r;
}

__device__ __forceinline__ short f2bf_trunc(float f) {  // 1 op; bias cancels via l
  union { float f; unsigned u; } c; c.f = f;
  return (short)(unsigned short)(c.u >> 16);
}

// async 16B global -> LDS (dest = wave-uniform base + lane*16)
__device__ __forceinline__ void llds16(const short* g, short* l) {
  __builtin_amdgcn_global_load_lds(
      (const __attribute__((address_space(1))) unsigned int*)g,
      (__attribute__((address_space(3))) unsigned int*)l, 16, 0, 0);
}

__global__ __launch_bounds__(256) void cast_f32_to_bf16(
    const float* __restrict__ src, short* __restrict__ dst, int n4) {
  int i = blockIdx.x * 256 + threadIdx.x;
  if (i >= n4) return;
  float4 f = ((const float4*)src)[i];
  short4 o;
  o.x = f2bf(f.x); o.y = f2bf(f.y); o.z = f2bf(f.z); o.w = f2bf(f.w);
  ((short4*)dst)[i] = o;
}

// ---------------------------------------------------------------------------
// QKV GEMM (B^T): C[m,n] = sum_k A[m,k]*Bw[n,k]. 128x128 tile, BK=32,
// DOUBLE-BUFFERED staging (1 barrier/iter), XOR-swizzled, LDS union with
// corner-turn epilogue (34 KB total -> 4 blocks/CU). Q/K: row-major lC ->
// [B,H,T,D] (K pre-scaled by SL2E). V (n0>=2048): transposed lCt -> Vt.
// ---------------------------------------------------------------------------
__global__ __launch_bounds__(256) void gemm_qkv(
    const short* __restrict__ A, const short* __restrict__ Bw,
    short* __restrict__ Qo, short* __restrict__ Ko, short* __restrict__ Vt) {
  const int K = 1024;
  __shared__ short smem[17408];  // [buf0: A 4096|B 4096][buf1: A 4096|B 4096] | lC/lCt
  const int tid = threadIdx.x;
  const int lane = tid & 63;
  const int wave = tid >> 6;
  const int m0 = blockIdx.y * 128;
  const int n0 = blockIdx.x * 128;
  const int wm = (wave >> 1) * 64;
  const int wn = (wave & 1) * 64;
  const int mrow = lane & 15;
  const int kq = lane >> 4;

  f32x4 acc[4][4];
#pragma unroll
  for (int i = 0; i < 4; ++i)
#pragma unroll
    for (int j = 0; j < 4; ++j) acc[i][j] = (f32x4){0.f, 0.f, 0.f, 0.f};

  // stage tile it (k0 = it*32) into buffer buf: 512 chunks of 8 shorts each
  auto stage = [&](int it, int buf) {
#pragma unroll
    for (int call = 0; call < 2; ++call) {
      const int cb = call * 256 + wave * 64;
      const int c = cb + lane;
      const int row = c >> 2;
      const int scol = (c & 3) ^ (row & 3);
      llds16(A + (size_t)(m0 + row) * K + it * 32 + scol * 8,
             &smem[buf * 8192 + cb * 8]);
      llds16(Bw + (size_t)(n0 + row) * K + it * 32 + scol * 8,
             &smem[buf * 8192 + 4096 + cb * 8]);
    }
  };

  stage(0, 0);
  __syncthreads();

  for (int it = 0; it < 32; ++it) {
    const int buf = it & 1;
    if (it < 31) stage(it + 1, buf ^ 1);
    const short* lA = &smem[buf * 8192];
    const short* lB = &smem[buf * 8192 + 4096];
    bf16x8 af[4], bfr[4];
#pragma unroll
    for (int i = 0; i < 4; ++i) {
      const int row = wm + i * 16 + mrow;
      af[i] = *(const bf16x8*)&lA[row * 32 + ((kq ^ (row & 3)) * 8)];
    }
#pragma unroll
    for (int j = 0; j < 4; ++j) {
      const int row = wn + j * 16 + mrow;
      bfr[j] = *(const bf16x8*)&lB[row * 32 + ((kq ^ (row & 3)) * 8)];
    }
#pragma unroll
    for (int i = 0; i < 4; ++i)
#pragma unroll
      for (int j = 0; j < 4; ++j)
        acc[i][j] = __builtin_amdgcn_mfma_f32_16x16x32_bf16(af[i], bfr[j], acc[i][j], 0, 0, 0);
    __syncthreads();
  }

  const int b = m0 >> 11;            // whole tile lies in one batch
  if (n0 < 2048) {
    // Q/K block: row-major corner-turn (stride 132), coalesced 16B stores
    short* lC = smem;
#pragma unroll
    for (int i = 0; i < 4; ++i) {
      const int row = wm + i * 16 + kq * 4;
#pragma unroll
      for (int j = 0; j < 4; ++j) {
        const int col = wn + j * 16 + mrow;
        const float sc_ = (((n0 + col) >> 10) == 1) ? SL2E : 1.0f;
#pragma unroll
        for (int r = 0; r < 4; ++r)
          lC[(row + r) * 132 + col] = f2bf(acc[i][j][r] * sc_);
      }
    }
    __syncthreads();
#pragma unroll
    for (int call = 0; call < 8; ++call) {
      const int cc = call * 256 + tid;
      const int row = cc >> 4;
      const int t = (m0 + row) & 2047;
      const int o = n0 + (cc & 15) * 8;
      const int c = o & 1023;
      const int h = c >> 6;
      const int d = c & 63;
      short* dst = (o >> 10) == 0 ? Qo : Ko;
      bf16x8 val = *(const bf16x8*)&lC[row * 132 + (cc & 15) * 8];
      *(bf16x8*)(dst + ((size_t)(b * 16 + h) * 2048 + t) * 64 + d) = val;
    }
  } else {
    // V block: transposed corner-turn (lCt[col][row], stride 136) -> Vt [bh][d][t]
    short* lCt = smem;
#pragma unroll
    for (int i = 0; i < 4; ++i) {
      const int row = wm + i * 16 + kq * 4;
#pragma unroll
      for (int j = 0; j < 4; ++j) {
        const int col = wn + j * 16 + mrow;
#pragma unroll
        for (int r = 0; r < 4; ++r)
          lCt[col * 136 + row + r] = f2bf(acc[i][j][r]);
      }
    }
    __syncthreads();
#pragma unroll
    for (int call = 0; call < 8; ++call) {
      const int cc = call * 256 + tid;
      const int col = cc >> 4;
      const int tg = cc & 15;
      const int o = n0 + col;           // 2048..3071
      const int d = o & 63;
      const int h = (o >> 6) & 15;
      const int t = (m0 & 2047) + tg * 8;   // batch offset lives in bh, not t
      bf16x8 val = *(const bf16x8*)&lCt[col * 136 + tg * 8];
      *(bf16x8*)(Vt + ((size_t)(b * 16 + h) * 64 + d) * 2048 + t) = val;
    }
  }
}

// Out-proj GEMM: M=8192, N=1024, BK=32, double-buffered staging, + bias, fp32.
__global__ __launch_bounds__(256) void gemm_out(
    const short* __restrict__ A, const short* __restrict__ Bw,
    const float* __restrict__ bias, float* __restrict__ Out) {
  const int K = 1024;
  __shared__ short smem[16384];
  const int tid = threadIdx.x;
  const int lane = tid & 63;
  const int wave = tid >> 6;
  const int m0 = blockIdx.y * 128;
  const int n0 = blockIdx.x * 128;
  const int wm = (wave >> 1) * 64;
  const int wn = (wave & 1) * 64;
  const int mrow = lane & 15;
  const int kq = lane >> 4;

  f32x4 acc[4][4];
#pragma unroll
  for (int i = 0; i < 4; ++i)
#pragma unroll
    for (int j = 0; j < 4; ++j) acc[i][j] = (f32x4){0.f, 0.f, 0.f, 0.f};

  auto stage = [&](int it, int buf) {
#pragma unroll
    for (int call = 0; call < 2; ++call) {
      const int cb = call * 256 + wave * 64;
      const int c = cb + lane;
      const int row = c >> 2;
      const int scol = (c & 3) ^ (row & 3);
      llds16(A + (size_t)(m0 + row) * K + it * 32 + scol * 8,
             &smem[buf * 8192 + cb * 8]);
      llds16(Bw + (size_t)(n0 + row) * K + it * 32 + scol * 8,
             &smem[buf * 8192 + 4096 + cb * 8]);
    }
  };

  stage(0, 0);
  __syncthreads();

  for (int it = 0; it < 32; ++it) {
    const int buf = it & 1;
    if (it < 31) stage(it + 1, buf ^ 1);
    const short* lA = &smem[buf * 8192];
    const short* lB = &smem[buf * 8192 + 4096];
    bf16x8 af[4], bfr[4];
#pragma unroll
    for (int i = 0; i < 4; ++i) {
      const int row = wm + i * 16 + mrow;
      af[i] = *(const bf16x8*)&lA[row * 32 + ((kq ^ (row & 3)) * 8)];
    }
#pragma unroll
    for (int j = 0; j < 4; ++j) {
      const int row = wn + j * 16 + mrow;
      bfr[j] = *(const bf16x8*)&lB[row * 32 + ((kq ^ (row & 3)) * 8)];
    }
#pragma unroll
    for (int i = 0; i < 4; ++i)
#pragma unroll
      for (int j = 0; j < 4; ++j)
        acc[i][j] = __builtin_amdgcn_mfma_f32_16x16x32_bf16(af[i], bfr[j], acc[i][j], 0, 0, 0);
    __syncthreads();
  }

#pragma unroll
  for (int i = 0; i < 4; ++i) {
    const int m = m0 + wm + i * 16 + kq * 4;
#pragma unroll
    for (int j = 0; j < 4; ++j) {
      const int n = n0 + wn + j * 16 + mrow;
      const float bb = bias[n];
#pragma unroll
      for (int r = 0; r < 4; ++r)
        Out[(size_t)(m + r) * 1024 + n] = acc[i][j][r] + bb;
    }
  }
}

// ---------------------------------------------------------------------------
// Flash attention R8. Grid (64 bh, 8). Block handles FOUR q-tiles
// {bx, 31-bx, 15-bx, 16+bx} (constant 66 seg-iterations) sharing one staged
// K/Vt stream (kt = 0..31-bx). Fixed-max softmax (M=15 via MFMA C-init);
// l via ones-MFMA over packed P; truncating pack; XOR-swizzled K/Vt LDS;
// double-buffered staging, one barrier per kt.
// ---------------------------------------------------------------------------
__global__ __launch_bounds__(256) void flash_attn(
    const short* __restrict__ Qg, const short* __restrict__ Kg,
    const short* __restrict__ Vtg, short* __restrict__ Og) {
  const int T = 2048;
  __shared__ short lK[2][64 * 64];
  __shared__ short lVt[2][64 * 64];
  __shared__ short lP[4 * 16 * 76];
  const int tid = threadIdx.x;
  const int lane = tid & 63;
  const int wave = tid >> 6;
  const int bh = blockIdx.x;
  const int bx = blockIdx.y;         // 0..7
  const int mrow = lane & 15;
  const int kq = lane >> 4;
  const int swz = mrow & 7;
  const size_t base = (size_t)bh * T * 64;   // Q,K: [bh][t][d]
  const size_t vbase = (size_t)bh * 64 * T;  // Vt:  [bh][d][t]

  int qts[4];
  qts[0] = bx;
  qts[1] = 31 - bx;   // max
  qts[2] = 15 - bx;
  qts[3] = 16 + bx;

  const bf16x8 ones = {0x3F80, 0x3F80, 0x3F80, 0x3F80, 0x3F80, 0x3F80, 0x3F80, 0x3F80};

  bf16x8 aq0[4], aq1[4];
#pragma unroll
  for (int s = 0; s < 4; ++s) {
    const short* qp = Qg + base + (size_t)(qts[s] * 64 + wave * 16 + mrow) * 64 + kq * 8;
    aq0[s] = *(const bf16x8*)qp;
    aq1[s] = *(const bf16x8*)(qp + 32);
  }

  f32x4 acc[4][4], lac[4];
#pragma unroll
  for (int s = 0; s < 4; ++s) {
    lac[s] = (f32x4){0.f, 0.f, 0.f, 0.f};
#pragma unroll
    for (int jd = 0; jd < 4; ++jd) acc[s][jd] = (f32x4){0.f, 0.f, 0.f, 0.f};
  }

  auto stage = [&](int nt, int buf) {
#pragma unroll
    for (int call = 0; call < 2; ++call) {
      const int cb = call * 256 + wave * 64;
      const int c = cb + lane;
      const int row = c >> 3;
      const int scol = (c & 7) ^ (row & 7);
      llds16(Kg + base + (size_t)(nt * 64 + row) * 64 + scol * 8, &lK[buf][cb * 8]);
      llds16(Vtg + vbase + (size_t)row * T + nt * 64 + scol * 8, &lVt[buf][cb * 8]);
    }
  };

  stage(0, 0);
  __syncthreads();

  const int ktmax = qts[1];
  for (int kt = 0; kt <= ktmax; ++kt) {
    const int bcur = kt & 1;
    if (kt < ktmax) stage(kt + 1, bcur ^ 1);
    const short* K_ = lK[bcur];
    const short* Vt_ = lVt[bcur];

#pragma unroll
    for (int s = 0; s < 4; ++s) {
      const int qt = qts[s];
      if (kt > qt) continue;

      f32x4 sc[4];
#pragma unroll
      for (int j = 0; j < 4; ++j) {
        const short* krow = &K_[(j * 16 + mrow) * 64];
        bf16x8 kb0 = *(const bf16x8*)&krow[(kq ^ swz) * 8];
        bf16x8 kb1 = *(const bf16x8*)&krow[((4 + kq) ^ swz) * 8];
        f32x4 ss = (f32x4){-FIXED_M, -FIXED_M, -FIXED_M, -FIXED_M};
        ss = __builtin_amdgcn_mfma_f32_16x16x32_bf16(aq0[s], kb0, ss, 0, 0, 0);
        ss = __builtin_amdgcn_mfma_f32_16x16x32_bf16(aq1[s], kb1, ss, 0, 0, 0);
        sc[j] = ss;
      }

      if (kt == qt) {  // diagonal tile: causal mask
        const int qrow = qt * 64 + wave * 16 + kq * 4;
#pragma unroll
        for (int j = 0; j < 4; ++j) {
          const int key = kt * 64 + j * 16 + mrow;
#pragma unroll
          for (int r = 0; r < 4; ++r)
            if (key > qrow + r) sc[j][r] = -1e30f;
        }
      }

      // P = exp2(sc); truncate-pack to LDS (stride 76)
      short* pw = &lP[wave * 1216];
#pragma unroll
      for (int j = 0; j < 4; ++j)
#pragma unroll
        for (int r = 0; r < 4; ++r)
          pw[(kq * 4 + r) * 76 + j * 16 + mrow] = f2bf_trunc(EXP2F(sc[j][r]));

      // PV + l (l = packed-P . ones via MFMA)
      bf16x8 pa0 = *(const bf16x8*)&lP[wave * 1216 + mrow * 76 + kq * 8];
      bf16x8 pa1 = *(const bf16x8*)&lP[wave * 1216 + mrow * 76 + 32 + kq * 8];
      lac[s] = __builtin_amdgcn_mfma_f32_16x16x32_bf16(pa0, ones, lac[s], 0, 0, 0);
      lac[s] = __builtin_amdgcn_mfma_f32_16x16x32_bf16(pa1, ones, lac[s], 0, 0, 0);
#pragma unroll
      for (int jd = 0; jd < 4; ++jd) {
        const short* vrow = &Vt_[(jd * 16 + mrow) * 64];
        bf16x8 vb0 = *(const bf16x8*)&vrow[(kq ^ swz) * 8];
        bf16x8 vb1 = *(const bf16x8*)&vrow[((4 + kq) ^ swz) * 8];
        acc[s][jd] = __builtin_amdgcn_mfma_f32_16x16x32_bf16(pa0, vb0, acc[s][jd], 0, 0, 0);
        acc[s][jd] = __builtin_amdgcn_mfma_f32_16x16x32_bf16(pa1, vb1, acc[s][jd], 0, 0, 0);
      }
    }
    __syncthreads();
  }

  const int b = bh >> 4;
  const int h = bh & 15;
#pragma unroll
  for (int s = 0; s < 4; ++s) {
#pragma unroll
    for (int r = 0; r < 4; ++r) {
      const float inv = 1.0f / lac[s][r];
      const int t = qts[s] * 64 + wave * 16 + kq * 4 + r;
#pragma unroll
      for (int jd = 0; jd < 4; ++jd) {
        const int col = h * 64 + jd * 16 + mrow;
        Og[((size_t)b * 2048 + t) * 1024 + col] = f2bf(acc[s][jd][r] * inv);
      }
    }
  }
}

extern "C" void kernel_launch(void* const* d_in, const int* in_sizes, int n_in,
                              void* d_out, int out_size, void* d_ws, size_t ws_size,
                              hipStream_t stream) {
  const float* x = (const float*)d_in[0];
  const float* w_qkv = (const float*)d_in[1];
  const float* w_out = (const float*)d_in[2];
  const float* b_out = (const float*)d_in[3];
  float* out = (float*)d_out;

  char* ws = (char*)d_ws;
  const size_t NX = 8192ull * 1024;
  const size_t NWQ = 3072ull * 1024;
  const size_t NWO = 1024ull * 1024;
  const size_t NQ = 64ull * 2048 * 64;
  size_t off = 0;
  short* xb    = (short*)(ws + off); off += NX * 2;
  short* wqkvb = (short*)(ws + off); off += NWQ * 2;
  short* woutb = (short*)(ws + off); off += NWO * 2;
  short* q     = (short*)(ws + off); off += NQ * 2;
  short* k     = (short*)(ws + off); off += NQ * 2;
  short* vt    = (short*)(ws + off); off += NQ * 2;  // V stored transposed [bh][d][t]
  short* attb  = (short*)(ws + off); off += NX * 2;
  if (off > ws_size) return;

  cast_f32_to_bf16<<<(int)(NX / 4 / 256), 256, 0, stream>>>(x, xb, (int)(NX / 4));
  cast_f32_to_bf16<<<(int)(NWQ / 4 / 256), 256, 0, stream>>>(w_qkv, wqkvb, (int)(NWQ / 4));
  cast_f32_to_bf16<<<(int)(NWO / 4 / 256), 256, 0, stream>>>(w_out, woutb, (int)(NWO / 4));
  gemm_qkv<<<dim3(24, 64), 256, 0, stream>>>(xb, wqkvb, q, k, vt);
  flash_attn<<<dim3(64, 8), 256, 0, stream>>>(q, k, vt, attb);
  gemm_out<<<dim3(8, 64), 256, 0, stream>>>(attb, woutb, b_out, out);
}